// Round 2
// baseline (487.499 us; speedup 1.0000x reference)
//
#include <hip/hip_runtime.h>
#include <hip/hip_bf16.h>

#define D_MODEL   1024
#define D_STATE   128
#define D_INNER   2048
#define NHEADS    32
#define HEADDIM   64
#define D_IN_PROJ 4384   // 2*D_INNER + 2*D_STATE + NHEADS
#define CONV_DIM  2304   // D_INNER + 2*D_STATE
#define BATCH     2
#define SEQLEN    512
#define M_TOKENS  (BATCH*SEQLEN)   // 1024
#define EPS       1e-5f
#define NSPLIT    4

typedef __bf16 bf16x8 __attribute__((ext_vector_type(8)));
typedef float  f32x4  __attribute__((ext_vector_type(4)));

__device__ __forceinline__ ushort f2bf(float f) {
  union { float f; unsigned int i; } v; v.f = f;
  unsigned int x = v.i;
  return (ushort)((x + 0x7fffu + ((x >> 16) & 1u)) >> 16);
}

// ---------------------------------------------------------------------------
// fp32 -> bf16 conversion, 8 elems/thread, n must be divisible by 8
// ---------------------------------------------------------------------------
__global__ __launch_bounds__(256) void cvt_f32_bf16(const float* __restrict__ src,
                                                    ushort* __restrict__ dst, int n) {
  const int i = (blockIdx.x * 256 + threadIdx.x) * 8;
  if (i >= n) return;
  const float4 a = *(const float4*)(src + i);
  const float4 b = *(const float4*)(src + i + 4);
  uint4 v;
  v.x = (unsigned)f2bf(a.x) | ((unsigned)f2bf(a.y) << 16);
  v.y = (unsigned)f2bf(a.z) | ((unsigned)f2bf(a.w) << 16);
  v.z = (unsigned)f2bf(b.x) | ((unsigned)f2bf(b.y) << 16);
  v.w = (unsigned)f2bf(b.z) | ((unsigned)f2bf(b.w) << 16);
  *(uint4*)(dst + i) = v;
}

// ---------------------------------------------------------------------------
// C[m][n] = sum_k A[m][k] * Bt[n][k]   (both K-contiguous bf16, fp32 out)
// block = 256 threads (4 waves); tile 64(m) x 32(n); wave w -> rows [w*16,w*16+16)
// mfma_f32_16x16x32_bf16 layouts (guide §3, m89/m91-verified):
//   A: lane holds A[m=lane&15][k = (lane>>4)*8 + j]
//   B: lane holds B[k=(lane>>4)*8+j][n=lane&15]  == Bt[n=lane&15][k]
//   D: d[r] -> C[row=(lane>>4)*4+r][col=lane&15]
// ---------------------------------------------------------------------------
template <int OUT_BF16>
__global__ __launch_bounds__(256) void gemm_bt(const ushort* __restrict__ A,
                                               const ushort* __restrict__ Bt,
                                               void* __restrict__ Cout,
                                               int M, int N, int K) {
  const int n0   = blockIdx.x * 32;
  const int m0   = blockIdx.y * 64;
  const int tid  = threadIdx.x;
  const int lane = tid & 63;
  const int wave = tid >> 6;
  const int r16  = lane & 15;
  const int q    = lane >> 4;

  const ushort* Ap  = A  + (size_t)(m0 + wave * 16 + r16) * K + q * 8;
  const ushort* Bp0 = Bt + (size_t)(n0 + r16) * K + q * 8;
  const ushort* Bp1 = Bp0 + (size_t)16 * K;

  f32x4 acc0 = {0.f, 0.f, 0.f, 0.f};
  f32x4 acc1 = {0.f, 0.f, 0.f, 0.f};
  #pragma unroll 4
  for (int k = 0; k < K; k += 32) {
    bf16x8 a  = *(const bf16x8*)(const void*)(Ap + k);
    bf16x8 b0 = *(const bf16x8*)(const void*)(Bp0 + k);
    bf16x8 b1 = *(const bf16x8*)(const void*)(Bp1 + k);
    acc0 = __builtin_amdgcn_mfma_f32_16x16x32_bf16(a, b0, acc0, 0, 0, 0);
    acc1 = __builtin_amdgcn_mfma_f32_16x16x32_bf16(a, b1, acc1, 0, 0, 0);
  }

  const int crow = m0 + wave * 16 + q * 4;
  const int ccol = n0 + r16;
  if (OUT_BF16) {
    ushort* C = (ushort*)Cout;
    #pragma unroll
    for (int r = 0; r < 4; ++r) {
      C[(size_t)(crow + r) * N + ccol]      = f2bf(acc0[r]);
      C[(size_t)(crow + r) * N + ccol + 16] = f2bf(acc1[r]);
    }
  } else {
    float* C = (float*)Cout;
    #pragma unroll
    for (int r = 0; r < 4; ++r) {
      C[(size_t)(crow + r) * N + ccol]      = acc0[r];
      C[(size_t)(crow + r) * N + ccol + 16] = acc1[r];
    }
  }
}

// ---------------------------------------------------------------------------
// causal depthwise conv (k=4) + bias + SiLU over xBC slice of zxbcdt -> fp32
// ---------------------------------------------------------------------------
__global__ __launch_bounds__(256) void conv_silu(const float* __restrict__ zx,
                                                 const float* __restrict__ cw,
                                                 const float* __restrict__ cb,
                                                 float* __restrict__ xbc) {
  const int idx = blockIdx.x * 256 + threadIdx.x;     // over M_TOKENS*CONV_DIM
  const int c   = idx % CONV_DIM;
  const int bt  = idx / CONV_DIM;
  const int t   = bt % SEQLEN;

  float acc = cb[c];
  #pragma unroll
  for (int k = 0; k < 4; ++k) {
    const int tt = t - 3 + k;
    if (tt >= 0) {
      acc += zx[(size_t)(bt - 3 + k) * D_IN_PROJ + D_INNER + c] * cw[c * 4 + k];
    }
  }
  xbc[idx] = acc / (1.f + __expf(-acc));   // silu
}

// ---------------------------------------------------------------------------
// sequential SSM scan. grid = BATCH*NHEADS*NSPLIT blocks, 512 threads.
// thread: p = tid&63 (headdim), nsub = tid>>6 (0..7), 4 state elems (regs).
// per-step: in-thread partial dot over 4 n; LDS reduce over 8 nsub (dbuf,
// single barrier); per-split partial y written to global; splits combined later.
// ---------------------------------------------------------------------------
__global__ __launch_bounds__(512) void scan(const float* __restrict__ zx,
                                            const float* __restrict__ xbc,
                                            const float* __restrict__ dt_bias,
                                            const float* __restrict__ A_log,
                                            float* __restrict__ ypart) {
  const int blk   = blockIdx.x;
  const int split = blk & (NSPLIT - 1);
  const int h     = (blk >> 2) & (NHEADS - 1);
  const int b     = blk >> 7;
  const int tid   = threadIdx.x;
  const int p     = tid & 63;
  const int nsub  = tid >> 6;
  const int nbase = split * 32 + nsub * 4;

  __shared__ float dts[SEQLEN];
  __shared__ float dAs[SEQLEN];
  __shared__ float red[2][512];

  const float dtb = dt_bias[h];
  const float An  = -__expf(A_log[h]);     // A = -exp(A_log)
  for (int t = tid; t < SEQLEN; t += 512) {
    float raw = zx[(size_t)(b * SEQLEN + t) * D_IN_PROJ + (D_INNER + CONV_DIM) + h] + dtb;
    float sp  = (raw > 20.f) ? raw : log1pf(__expf(raw));   // softplus
    dts[t] = sp;
    dAs[t] = __expf(sp * An);
  }
  __syncthreads();

  float s0 = 0.f, s1 = 0.f, s2 = 0.f, s3 = 0.f;
  const float* base = xbc + (size_t)b * SEQLEN * CONV_DIM;
  float* yout = ypart + (size_t)(split * M_TOKENS + b * SEQLEN) * D_INNER + h * HEADDIM + p;

  for (int t = 0; t < SEQLEN; ++t) {
    const float* row = base + (size_t)t * CONV_DIM;
    const float xv = row[h * HEADDIM + p];
    const float4 Bv = *(const float4*)(row + D_INNER + nbase);
    const float4 Cv = *(const float4*)(row + D_INNER + D_STATE + nbase);
    const float dtv = dts[t];
    const float dAv = dAs[t];
    const float cc  = dtv * xv;
    s0 = fmaf(s0, dAv, cc * Bv.x);
    s1 = fmaf(s1, dAv, cc * Bv.y);
    s2 = fmaf(s2, dAv, cc * Bv.z);
    s3 = fmaf(s3, dAv, cc * Bv.w);
    const float part = s0 * Cv.x + s1 * Cv.y + s2 * Cv.z + s3 * Cv.w;
    red[t & 1][tid] = part;
    __syncthreads();
    if (nsub == 0) {
      float y = 0.f;
      #pragma unroll
      for (int j = 0; j < 8; ++j) y += red[t & 1][j * 64 + p];
      yout[(size_t)t * D_INNER] = y;
    }
  }
}

// ---------------------------------------------------------------------------
// combine NSPLIT partials + D*x, gate with silu(z), RMSNorm, -> bf16 yn
// grid = M_TOKENS blocks x 256 threads (8 elems/thread over D_INNER)
// ---------------------------------------------------------------------------
__global__ __launch_bounds__(256) void gate_norm(const float* __restrict__ ypart,
                                                 const float* __restrict__ zx,
                                                 const float* __restrict__ xbc,
                                                 const float* __restrict__ Dp,
                                                 const float* __restrict__ nw,
                                                 ushort* __restrict__ yn) {
  const int row = blockIdx.x;
  const int tid = threadIdx.x;
  float vals[8];
  float ss = 0.f;
  #pragma unroll
  for (int i = 0; i < 8; ++i) {
    const int e = tid + i * 256;
    float y = ypart[(size_t)row * D_INNER + e]
            + ypart[(size_t)(1 * M_TOKENS + row) * D_INNER + e]
            + ypart[(size_t)(2 * M_TOKENS + row) * D_INNER + e]
            + ypart[(size_t)(3 * M_TOKENS + row) * D_INNER + e];
    const float xv = xbc[(size_t)row * CONV_DIM + e];
    y = fmaf(Dp[e >> 6], xv, y);
    const float z = zx[(size_t)row * D_IN_PROJ + e];
    const float g = z / (1.f + __expf(-z));   // silu(z)
    const float yg = y * g;
    vals[i] = yg;
    ss = fmaf(yg, yg, ss);
  }
  for (int o = 32; o > 0; o >>= 1) ss += __shfl_down(ss, o);
  __shared__ float wsum[4];
  if ((tid & 63) == 0) wsum[tid >> 6] = ss;
  __syncthreads();
  const float tot = wsum[0] + wsum[1] + wsum[2] + wsum[3];
  const float rms = rsqrtf(tot * (1.f / D_INNER) + EPS);
  #pragma unroll
  for (int i = 0; i < 8; ++i) {
    const int e = tid + i * 256;
    yn[(size_t)row * D_INNER + e] = f2bf(vals[i] * rms * nw[e]);
  }
}

// ---------------------------------------------------------------------------
extern "C" void kernel_launch(void* const* d_in, const int* in_sizes, int n_in,
                              void* d_out, int out_size, void* d_ws, size_t ws_size,
                              hipStream_t stream) {
  const float* u       = (const float*)d_in[0];
  const float* W_in    = (const float*)d_in[1];
  const float* conv_w  = (const float*)d_in[2];
  const float* conv_b  = (const float*)d_in[3];
  const float* dt_bias = (const float*)d_in[4];
  const float* A_log   = (const float*)d_in[5];
  const float* D_par   = (const float*)d_in[6];
  const float* norm_w  = (const float*)d_in[7];
  const float* W_out   = (const float*)d_in[8];
  float* out = (float*)d_out;

  char* ws = (char*)d_ws;
  // ws layout (bytes), all 16B-aligned:
  //   zx      : fp32 [1024][4384]   = 17,956,864
  //   xbc     : fp32 [1024][2304]   =  9,437,184
  //   ypart   : fp32 [4][1024][2048]= 33,554,432
  //   yn      : bf16 [1024][2048]   =  4,194,304
  //   u_bf    : bf16 [1024][1024]   =  2,097,152
  //   Win_bf  : bf16 [4384][1024]   =  8,978,432
  //   Wout_bf : bf16 [1024][2048]   =  4,194,304   (total ~76.7 MiB)
  float*  zx      = (float*)ws;
  float*  xbc     = (float*)(ws + 17956864);
  float*  ypart   = (float*)(ws + 17956864 + 9437184);
  ushort* yn      = (ushort*)(ws + 17956864 + 9437184 + 33554432);
  ushort* u_bf    = (ushort*)(ws + 17956864 + 9437184 + 33554432 + 4194304);
  ushort* Win_bf  = (ushort*)(ws + 17956864 + 9437184 + 33554432 + 4194304 + 2097152);
  ushort* Wout_bf = (ushort*)(ws + 17956864 + 9437184 + 33554432 + 4194304 + 2097152 + 8978432);

  cvt_f32_bf16<<<(M_TOKENS * D_MODEL) / (256 * 8), 256, 0, stream>>>(u, u_bf, M_TOKENS * D_MODEL);
  cvt_f32_bf16<<<(D_IN_PROJ * D_MODEL) / (256 * 8), 256, 0, stream>>>(W_in, Win_bf, D_IN_PROJ * D_MODEL);
  cvt_f32_bf16<<<(D_MODEL * D_INNER) / (256 * 8), 256, 0, stream>>>(W_out, Wout_bf, D_MODEL * D_INNER);

  gemm_bt<0><<<dim3(D_IN_PROJ / 32, M_TOKENS / 64), 256, 0, stream>>>(
      u_bf, Win_bf, (void*)zx, M_TOKENS, D_IN_PROJ, D_MODEL);
  conv_silu<<<(M_TOKENS * CONV_DIM) / 256, 256, 0, stream>>>(zx, conv_w, conv_b, xbc);
  scan<<<BATCH * NHEADS * NSPLIT, 512, 0, stream>>>(zx, xbc, dt_bias, A_log, ypart);
  gate_norm<<<M_TOKENS, 256, 0, stream>>>(ypart, zx, xbc, D_par, norm_w, yn);
  gemm_bt<0><<<dim3(D_MODEL / 32, M_TOKENS / 64), 256, 0, stream>>>(
      yn, Wout_bf, (void*)out, M_TOKENS, D_MODEL, D_INNER);
}

// Round 3
// 380.784 us; speedup vs baseline: 1.2803x; 1.2803x over previous
//
#include <hip/hip_runtime.h>
#include <hip/hip_bf16.h>

#define D_MODEL   1024
#define D_STATE   128
#define D_INNER   2048
#define NHEADS    32
#define HEADDIM   64
#define D_IN_PROJ 4384   // 2*D_INNER + 2*D_STATE + NHEADS
#define CONV_DIM  2304   // D_INNER + 2*D_STATE
#define BATCH     2
#define SEQLEN    512
#define M_TOKENS  (BATCH*SEQLEN)   // 1024
#define EPS       1e-5f
#define TT        32               // scan time-tile
#define NT        (SEQLEN/TT)      // 16 tiles

typedef __bf16 bf16x8 __attribute__((ext_vector_type(8)));
typedef float  f32x4  __attribute__((ext_vector_type(4)));

__device__ __forceinline__ ushort f2bf(float f) {
  union { float f; unsigned int i; } v; v.f = f;
  unsigned int x = v.i;
  return (ushort)((x + 0x7fffu + ((x >> 16) & 1u)) >> 16);
}

__device__ __forceinline__ void gload_lds16(const float* g, float* l) {
  __builtin_amdgcn_global_load_lds(
      (const __attribute__((address_space(1))) void*)g,
      (__attribute__((address_space(3))) void*)l, 16, 0, 0);
}

// ---------------------------------------------------------------------------
// fp32 -> bf16 conversion, 8 elems/thread
// ---------------------------------------------------------------------------
__global__ __launch_bounds__(256) void cvt_f32_bf16(const float* __restrict__ src,
                                                    ushort* __restrict__ dst, int n) {
  const int i = (blockIdx.x * 256 + threadIdx.x) * 8;
  if (i >= n) return;
  const float4 a = *(const float4*)(src + i);
  const float4 b = *(const float4*)(src + i + 4);
  uint4 v;
  v.x = (unsigned)f2bf(a.x) | ((unsigned)f2bf(a.y) << 16);
  v.y = (unsigned)f2bf(a.z) | ((unsigned)f2bf(a.w) << 16);
  v.z = (unsigned)f2bf(b.x) | ((unsigned)f2bf(b.y) << 16);
  v.w = (unsigned)f2bf(b.z) | ((unsigned)f2bf(b.w) << 16);
  *(uint4*)(dst + i) = v;
}

// ---------------------------------------------------------------------------
// C[m][n] = sum_k A[m][k] * Bt[n][k]   (both K-contiguous bf16, fp32 out)
// (unchanged from round 1 — isolating the scan delta this round)
// ---------------------------------------------------------------------------
template <int OUT_BF16>
__global__ __launch_bounds__(256) void gemm_bt(const ushort* __restrict__ A,
                                               const ushort* __restrict__ Bt,
                                               void* __restrict__ Cout,
                                               int M, int N, int K) {
  const int n0   = blockIdx.x * 32;
  const int m0   = blockIdx.y * 64;
  const int tid  = threadIdx.x;
  const int lane = tid & 63;
  const int wave = tid >> 6;
  const int r16  = lane & 15;
  const int q    = lane >> 4;

  const ushort* Ap  = A  + (size_t)(m0 + wave * 16 + r16) * K + q * 8;
  const ushort* Bp0 = Bt + (size_t)(n0 + r16) * K + q * 8;
  const ushort* Bp1 = Bp0 + (size_t)16 * K;

  f32x4 acc0 = {0.f, 0.f, 0.f, 0.f};
  f32x4 acc1 = {0.f, 0.f, 0.f, 0.f};
  #pragma unroll 4
  for (int k = 0; k < K; k += 32) {
    bf16x8 a  = *(const bf16x8*)(const void*)(Ap + k);
    bf16x8 b0 = *(const bf16x8*)(const void*)(Bp0 + k);
    bf16x8 b1 = *(const bf16x8*)(const void*)(Bp1 + k);
    acc0 = __builtin_amdgcn_mfma_f32_16x16x32_bf16(a, b0, acc0, 0, 0, 0);
    acc1 = __builtin_amdgcn_mfma_f32_16x16x32_bf16(a, b1, acc1, 0, 0, 0);
  }

  const int crow = m0 + wave * 16 + q * 4;
  const int ccol = n0 + r16;
  if (OUT_BF16) {
    ushort* C = (ushort*)Cout;
    #pragma unroll
    for (int r = 0; r < 4; ++r) {
      C[(size_t)(crow + r) * N + ccol]      = f2bf(acc0[r]);
      C[(size_t)(crow + r) * N + ccol + 16] = f2bf(acc1[r]);
    }
  } else {
    float* C = (float*)Cout;
    #pragma unroll
    for (int r = 0; r < 4; ++r) {
      C[(size_t)(crow + r) * N + ccol]      = acc0[r];
      C[(size_t)(crow + r) * N + ccol + 16] = acc1[r];
    }
  }
}

// ---------------------------------------------------------------------------
// causal depthwise conv (k=4) + bias + SiLU over xBC slice of zxbcdt -> fp32
// ---------------------------------------------------------------------------
__global__ __launch_bounds__(256) void conv_silu(const float* __restrict__ zx,
                                                 const float* __restrict__ cw,
                                                 const float* __restrict__ cb,
                                                 float* __restrict__ xbc) {
  const int idx = blockIdx.x * 256 + threadIdx.x;     // over M_TOKENS*CONV_DIM
  const int c   = idx % CONV_DIM;
  const int bt  = idx / CONV_DIM;
  const int t   = bt % SEQLEN;

  float acc = cb[c];
  #pragma unroll
  for (int k = 0; k < 4; ++k) {
    const int tt = t - 3 + k;
    if (tt >= 0) {
      acc += zx[(size_t)(bt - 3 + k) * D_IN_PROJ + D_INNER + c] * cw[c * 4 + k];
    }
  }
  xbc[idx] = acc / (1.f + __expf(-acc));   // silu
}

// ---------------------------------------------------------------------------
// sequential SSM scan, barrier-free inner loop.
// grid = 256 blocks: blk = b*128 + h*4 + pq  (pq = which 16-p quarter)
// block = 256 threads (4 waves). wave lane = pl*16 + ns:
//   pl in [0,4): p = pq*16 + wave*4 + pl
//   ns in [0,16): thread owns 8 states, n = j*64 + ns*4 + k (j<2, k<4)
// y[p] reduced over n by 4 intra-wave shuffles -> NO per-step barrier.
// B/C rows (256 contiguous floats at xbc[row][2048..2304)) staged per 32-step
// tile into double-buffered LDS via global_load_lds (in flight during compute;
// 2 barriers per 32 steps). Depth-1 register prefetch of LDS reads.
// ---------------------------------------------------------------------------
__global__ __launch_bounds__(256) void scan(const float* __restrict__ zx,
                                            const float* __restrict__ xbc,
                                            const float* __restrict__ dt_bias,
                                            const float* __restrict__ A_log,
                                            float* __restrict__ y) {
  const int blk  = blockIdx.x;
  const int pq   = blk & 3;
  const int h    = (blk >> 2) & 31;
  const int b    = blk >> 7;
  const int tid  = threadIdx.x;
  const int lane = tid & 63;
  const int wave = tid >> 6;
  const int ns   = lane & 15;
  const int pl   = lane >> 4;
  const int plocal = wave * 4 + pl;            // [0,16)

  __shared__ float  bcs[2][TT * 256];          // 64 KB: [tile][t][B(128)|C(128)]
  __shared__ float  xvs[2][TT * 16];           // 4 KB
  __shared__ float2 dtA[SEQLEN];               // 4 KB: (dt, exp(dt*A))

  const float dtb = dt_bias[h];
  const float An  = -__expf(A_log[h]);         // A = -exp(A_log)
  for (int t = tid; t < SEQLEN; t += 256) {
    float raw = zx[(size_t)(b * SEQLEN + t) * D_IN_PROJ + (D_INNER + CONV_DIM) + h] + dtb;
    float sp  = (raw > 20.f) ? raw : log1pf(__expf(raw));   // softplus
    dtA[t] = make_float2(sp, __expf(sp * An));
  }

  const float* bcsrc = xbc + (size_t)b * SEQLEN * CONV_DIM + D_INNER;
  const float* xsrc  = xbc + (size_t)b * SEQLEN * CONV_DIM + h * HEADDIM + pq * 16;

  // prologue: stage tile 0
  #pragma unroll
  for (int it = 0; it < 8; ++it) {
    const int idx = it * 256 + tid;
    gload_lds16(bcsrc + (size_t)(idx >> 6) * CONV_DIM + (idx & 63) * 4,
                &bcs[0][(it * 256 + wave * 64) * 4]);
  }
  if (tid < 128) {
    const float4 xv4 = *(const float4*)(xsrc + (size_t)(tid >> 2) * CONV_DIM + (tid & 3) * 4);
    *(float4*)&xvs[0][(tid >> 2) * 16 + (tid & 3) * 4] = xv4;
  }
  __syncthreads();

  float s0 = 0.f, s1 = 0.f, s2 = 0.f, s3 = 0.f;
  float s4 = 0.f, s5 = 0.f, s6 = 0.f, s7 = 0.f;
  float* ydst = y + (size_t)b * SEQLEN * D_INNER + h * HEADDIM + pq * 16 + plocal;

  for (int k = 0; k < NT; ++k) {
    const int pb = k & 1;
    const int t0 = k * TT;

    // issue next tile's staging (lands during this tile's compute)
    float4 xv4;
    if (k + 1 < NT) {
      const int t1 = t0 + TT;
      #pragma unroll
      for (int it = 0; it < 8; ++it) {
        const int idx = it * 256 + tid;
        gload_lds16(bcsrc + (size_t)(t1 + (idx >> 6)) * CONV_DIM + (idx & 63) * 4,
                    &bcs[pb ^ 1][(it * 256 + wave * 64) * 4]);
      }
      if (tid < 128)
        xv4 = *(const float4*)(xsrc + (size_t)(t1 + (tid >> 2)) * CONV_DIM + (tid & 3) * 4);
    }

    // compute TT steps, depth-1 LDS->reg prefetch
    const float* bcb = &bcs[pb][0];
    float4 B0 = *(const float4*)(bcb + ns * 4);
    float4 B1 = *(const float4*)(bcb + 64 + ns * 4);
    float4 C0 = *(const float4*)(bcb + 128 + ns * 4);
    float4 C1 = *(const float4*)(bcb + 192 + ns * 4);
    float  xvv = xvs[pb][plocal];
    float2 da  = dtA[t0];

    #pragma unroll
    for (int tl = 0; tl < TT; ++tl) {
      float4 nB0, nB1, nC0, nC1; float nxv; float2 nda;
      if (tl + 1 < TT) {
        const float* p = bcb + (tl + 1) * 256;
        nB0 = *(const float4*)(p + ns * 4);
        nB1 = *(const float4*)(p + 64 + ns * 4);
        nC0 = *(const float4*)(p + 128 + ns * 4);
        nC1 = *(const float4*)(p + 192 + ns * 4);
        nxv = xvs[pb][(tl + 1) * 16 + plocal];
        nda = dtA[t0 + tl + 1];
      }
      const float cc = da.x * xvv;
      s0 = fmaf(s0, da.y, cc * B0.x);
      s1 = fmaf(s1, da.y, cc * B0.y);
      s2 = fmaf(s2, da.y, cc * B0.z);
      s3 = fmaf(s3, da.y, cc * B0.w);
      s4 = fmaf(s4, da.y, cc * B1.x);
      s5 = fmaf(s5, da.y, cc * B1.y);
      s6 = fmaf(s6, da.y, cc * B1.z);
      s7 = fmaf(s7, da.y, cc * B1.w);
      float part = s0 * C0.x;
      part = fmaf(s1, C0.y, part);
      part = fmaf(s2, C0.z, part);
      part = fmaf(s3, C0.w, part);
      part = fmaf(s4, C1.x, part);
      part = fmaf(s5, C1.y, part);
      part = fmaf(s6, C1.z, part);
      part = fmaf(s7, C1.w, part);
      part += __shfl_xor(part, 1);
      part += __shfl_xor(part, 2);
      part += __shfl_xor(part, 4);
      part += __shfl_xor(part, 8);
      if (ns == 0) ydst[(size_t)(t0 + tl) * D_INNER] = part;
      if (tl + 1 < TT) {
        B0 = nB0; B1 = nB1; C0 = nC0; C1 = nC1; xvv = nxv; da = nda;
      }
    }

    if (k + 1 < NT && tid < 128)
      *(float4*)&xvs[pb ^ 1][(tid >> 2) * 16 + (tid & 3) * 4] = xv4;
    __syncthreads();   // drains next-tile global_load_lds + xv writes
  }
}

// ---------------------------------------------------------------------------
// y + D*x, gate with silu(z), RMSNorm, -> bf16 yn
// ---------------------------------------------------------------------------
__global__ __launch_bounds__(256) void gate_norm(const float* __restrict__ y,
                                                 const float* __restrict__ zx,
                                                 const float* __restrict__ xbc,
                                                 const float* __restrict__ Dp,
                                                 const float* __restrict__ nw,
                                                 ushort* __restrict__ yn) {
  const int row = blockIdx.x;
  const int tid = threadIdx.x;
  float vals[8];
  float ss = 0.f;
  #pragma unroll
  for (int i = 0; i < 8; ++i) {
    const int e = tid + i * 256;
    float yv = y[(size_t)row * D_INNER + e];
    const float xv = xbc[(size_t)row * CONV_DIM + e];
    yv = fmaf(Dp[e >> 6], xv, yv);
    const float z = zx[(size_t)row * D_IN_PROJ + e];
    const float g = z / (1.f + __expf(-z));   // silu(z)
    const float yg = yv * g;
    vals[i] = yg;
    ss = fmaf(yg, yg, ss);
  }
  for (int o = 32; o > 0; o >>= 1) ss += __shfl_down(ss, o);
  __shared__ float wsum[4];
  if ((tid & 63) == 0) wsum[tid >> 6] = ss;
  __syncthreads();
  const float tot = wsum[0] + wsum[1] + wsum[2] + wsum[3];
  const float rms = rsqrtf(tot * (1.f / D_INNER) + EPS);
  #pragma unroll
  for (int i = 0; i < 8; ++i) {
    const int e = tid + i * 256;
    yn[(size_t)row * D_INNER + e] = f2bf(vals[i] * rms * nw[e]);
  }
}

// ---------------------------------------------------------------------------
extern "C" void kernel_launch(void* const* d_in, const int* in_sizes, int n_in,
                              void* d_out, int out_size, void* d_ws, size_t ws_size,
                              hipStream_t stream) {
  const float* u       = (const float*)d_in[0];
  const float* W_in    = (const float*)d_in[1];
  const float* conv_w  = (const float*)d_in[2];
  const float* conv_b  = (const float*)d_in[3];
  const float* dt_bias = (const float*)d_in[4];
  const float* A_log   = (const float*)d_in[5];
  const float* D_par   = (const float*)d_in[6];
  const float* norm_w  = (const float*)d_in[7];
  const float* W_out   = (const float*)d_in[8];
  float* out = (float*)d_out;

  char* ws = (char*)d_ws;
  // ws layout (bytes), all 16B-aligned:
  //   zx      : fp32 [1024][4384]   = 17,956,864   @ 0
  //   xbc     : fp32 [1024][2304]   =  9,437,184   @ 17,956,864
  //   y       : fp32 [1024][2048]   =  8,388,608   @ 27,394,048
  //   yn      : bf16 [1024][2048]   =  4,194,304   @ 35,782,656
  //   u_bf    : bf16 [1024][1024]   =  2,097,152   @ 39,976,960
  //   Win_bf  : bf16 [4384][1024]   =  8,978,432   @ 42,074,112
  //   Wout_bf : bf16 [1024][2048]   =  4,194,304   @ 51,052,544  (end 55,246,848)
  float*  zx      = (float*)ws;
  float*  xbc     = (float*)(ws + 17956864);
  float*  yb      = (float*)(ws + 27394048);
  ushort* yn      = (ushort*)(ws + 35782656);
  ushort* u_bf    = (ushort*)(ws + 39976960);
  ushort* Win_bf  = (ushort*)(ws + 42074112);
  ushort* Wout_bf = (ushort*)(ws + 51052544);

  cvt_f32_bf16<<<(M_TOKENS * D_MODEL) / (256 * 8), 256, 0, stream>>>(u, u_bf, M_TOKENS * D_MODEL);
  cvt_f32_bf16<<<(D_IN_PROJ * D_MODEL) / (256 * 8), 256, 0, stream>>>(W_in, Win_bf, D_IN_PROJ * D_MODEL);
  cvt_f32_bf16<<<(D_MODEL * D_INNER) / (256 * 8), 256, 0, stream>>>(W_out, Wout_bf, D_MODEL * D_INNER);

  gemm_bt<0><<<dim3(D_IN_PROJ / 32, M_TOKENS / 64), 256, 0, stream>>>(
      u_bf, Win_bf, (void*)zx, M_TOKENS, D_IN_PROJ, D_MODEL);
  conv_silu<<<(M_TOKENS * CONV_DIM) / 256, 256, 0, stream>>>(zx, conv_w, conv_b, xbc);
  scan<<<BATCH * NHEADS * 4, 256, 0, stream>>>(zx, xbc, dt_bias, A_log, yb);
  gate_norm<<<M_TOKENS, 256, 0, stream>>>(yb, zx, xbc, D_par, norm_w, yn);
  gemm_bt<0><<<dim3(D_MODEL / 32, M_TOKENS / 64), 256, 0, stream>>>(
      yn, Wout_bf, (void*)out, M_TOKENS, D_MODEL, D_INNER);
}

// Round 4
// 253.755 us; speedup vs baseline: 1.9211x; 1.5006x over previous
//
#include <hip/hip_runtime.h>
#include <hip/hip_bf16.h>

#define D_MODEL   1024
#define D_STATE   128
#define D_INNER   2048
#define NHEADS    32
#define HEADDIM   64
#define D_IN_PROJ 4384   // 2*D_INNER + 2*D_STATE + NHEADS
#define NPROJ_PAD 4480   // 35*128 (GEMM tile padding; stores masked to 4384)
#define CONV_DIM  2304   // D_INNER + 2*D_STATE
#define BATCH     2
#define SEQLEN    512
#define M_TOKENS  (BATCH*SEQLEN)   // 1024
#define EPS       1e-5f
#define TT        32               // scan time-tile
#define NT        (SEQLEN/TT)      // 16 tiles

typedef __bf16 bf16x8 __attribute__((ext_vector_type(8)));
typedef float  f32x4  __attribute__((ext_vector_type(4)));

__device__ __forceinline__ ushort f2bf(float f) {
  union { float f; unsigned int i; } v; v.f = f;
  unsigned int x = v.i;
  return (ushort)((x + 0x7fffu + ((x >> 16) & 1u)) >> 16);
}

__device__ __forceinline__ void gload_lds16(const float* g, float* l) {
  __builtin_amdgcn_global_load_lds(
      (const __attribute__((address_space(1))) void*)g,
      (__attribute__((address_space(3))) void*)l, 16, 0, 0);
}
__device__ __forceinline__ void gload_lds16u(const ushort* g, ushort* l) {
  __builtin_amdgcn_global_load_lds(
      (const __attribute__((address_space(1))) void*)g,
      (__attribute__((address_space(3))) void*)l, 16, 0, 0);
}

// ---------------------------------------------------------------------------
// fp32 -> bf16 conversion, 8 elems/thread
// ---------------------------------------------------------------------------
__global__ __launch_bounds__(256) void cvt_f32_bf16(const float* __restrict__ src,
                                                    ushort* __restrict__ dst, int n) {
  const int i = (blockIdx.x * 256 + threadIdx.x) * 8;
  if (i >= n) return;
  const float4 a = *(const float4*)(src + i);
  const float4 b = *(const float4*)(src + i + 4);
  uint4 v;
  v.x = (unsigned)f2bf(a.x) | ((unsigned)f2bf(a.y) << 16);
  v.y = (unsigned)f2bf(a.z) | ((unsigned)f2bf(a.w) << 16);
  v.z = (unsigned)f2bf(b.x) | ((unsigned)f2bf(b.y) << 16);
  v.w = (unsigned)f2bf(b.z) | ((unsigned)f2bf(b.w) << 16);
  *(uint4*)(dst + i) = v;
}

// ---------------------------------------------------------------------------
// m97-style tiled GEMM: C[m][n] = sum_k A[m][k]*Bt[n][k], bf16 in, fp32 out.
// 256 thr / 4 waves in 2x2; BK=32; LDS staged via global_load_lds width=16.
// MASK_N: skip stores with col >= Nreal (N padded to grid tiles; OOB Bt rows
// read adjacent ws data — finite, masked out).
// ---------------------------------------------------------------------------
template <int BM, int BN, int MASK_N>
__global__ __launch_bounds__(256) void gemm_tile(const ushort* __restrict__ A,
                                                 const ushort* __restrict__ Bt,
                                                 float* __restrict__ C,
                                                 int Nreal, int K, int ldc) {
  constexpr int WM = BM / 2, WN = BN / 2, FM = WM / 16, FN = WN / 16;
  constexpr int LA = BM * 4 / 256, LB = BN * 4 / 256;
  __shared__ ushort As[BM * 32];
  __shared__ ushort Bs[BN * 32];
  const int tid = threadIdx.x, lane = tid & 63, wave = tid >> 6;
  const int r16 = lane & 15, q = lane >> 4;
  const int wm = wave & 1, wn = wave >> 1;
  const int m0 = blockIdx.y * BM, n0 = blockIdx.x * BN;

  f32x4 acc[FM][FN] = {};

  for (int k0 = 0; k0 < K; k0 += 32) {
    __syncthreads();   // previous iter's ds_reads done before LDS overwrite
    #pragma unroll
    for (int it = 0; it < LA; ++it) {
      const int idx = it * 256 + tid;
      gload_lds16u(A + (size_t)(m0 + (idx >> 2)) * K + k0 + (idx & 3) * 8,
                   As + (it * 256 + wave * 64) * 8);
    }
    #pragma unroll
    for (int it = 0; it < LB; ++it) {
      const int idx = it * 256 + tid;
      gload_lds16u(Bt + (size_t)(n0 + (idx >> 2)) * K + k0 + (idx & 3) * 8,
                   Bs + (it * 256 + wave * 64) * 8);
    }
    __syncthreads();   // drains global_load_lds

    bf16x8 af[FM], bfr[FN];
    #pragma unroll
    for (int i = 0; i < FM; ++i)
      af[i] = *(const bf16x8*)(const void*)(As + (wm * WM + i * 16 + r16) * 32 + q * 8);
    #pragma unroll
    for (int j = 0; j < FN; ++j)
      bfr[j] = *(const bf16x8*)(const void*)(Bs + (wn * WN + j * 16 + r16) * 32 + q * 8);
    #pragma unroll
    for (int i = 0; i < FM; ++i)
      #pragma unroll
      for (int j = 0; j < FN; ++j)
        acc[i][j] = __builtin_amdgcn_mfma_f32_16x16x32_bf16(af[i], bfr[j], acc[i][j], 0, 0, 0);
  }

  #pragma unroll
  for (int i = 0; i < FM; ++i) {
    const int row = m0 + wm * WM + i * 16 + q * 4;
    #pragma unroll
    for (int j = 0; j < FN; ++j) {
      const int col = n0 + wn * WN + j * 16 + r16;
      if (!MASK_N || col < Nreal) {
        #pragma unroll
        for (int r = 0; r < 4; ++r)
          C[(size_t)(row + r) * ldc + col] = acc[i][j][r];
      }
    }
  }
}

// ---------------------------------------------------------------------------
// causal depthwise conv (k=4) + bias + SiLU over xBC slice of zxbcdt -> fp32
// ---------------------------------------------------------------------------
__global__ __launch_bounds__(256) void conv_silu(const float* __restrict__ zx,
                                                 const float* __restrict__ cw,
                                                 const float* __restrict__ cb,
                                                 float* __restrict__ xbc) {
  const int idx = blockIdx.x * 256 + threadIdx.x;     // over M_TOKENS*CONV_DIM
  const int c   = idx % CONV_DIM;
  const int bt  = idx / CONV_DIM;
  const int t   = bt % SEQLEN;

  float acc = cb[c];
  #pragma unroll
  for (int k = 0; k < 4; ++k) {
    const int tt = t - 3 + k;
    if (tt >= 0) {
      acc += zx[(size_t)(bt - 3 + k) * D_IN_PROJ + D_INNER + c] * cw[c * 4 + k];
    }
  }
  xbc[idx] = acc / (1.f + __expf(-acc));   // silu
}

// ---------------------------------------------------------------------------
// sequential SSM scan v3.
// grid = 512: blk = b*256 + h*8 + pq*2 + nh
//   nh: which 64-wide n-half (cross-block partials summed in gate_norm)
//   pq: which 16-wide p-quarter
// block 256 thr / 4 waves; lane = pl*16+ns: plocal = wave*4+pl (16 p), ns<16.
// Thread owns 4 states (n = nh*64 + ns*4 + k). Steps processed in groups of
// 4: the 16 shfl_xor ops form 4 independent 4-deep chains (latency amortized).
// y goes to LDS (dbuf) and is flushed per-tile as coalesced float4 stores.
// B/C halves staged per 32-step tile into dbuf LDS via global_load_lds.
// ---------------------------------------------------------------------------
__global__ __launch_bounds__(256) void scan(const float* __restrict__ zx,
                                            const float* __restrict__ xbc,
                                            const float* __restrict__ dt_bias,
                                            const float* __restrict__ A_log,
                                            float* __restrict__ ypart) {
  const int blk  = blockIdx.x;
  const int nh   = blk & 1;
  const int pq   = (blk >> 1) & 3;
  const int h    = (blk >> 3) & 31;
  const int b    = blk >> 8;
  const int tid  = threadIdx.x;
  const int lane = tid & 63;
  const int wave = tid >> 6;
  const int ns   = lane & 15;
  const int pl   = lane >> 4;
  const int plocal = wave * 4 + pl;            // [0,16)

  __shared__ float  bcs[2][TT * 128];          // 32 KB: [t][B64|C64] for this n-half
  __shared__ float  xvs[2][TT * 16];           // 4 KB
  __shared__ float  yls[2][TT * 16];           // 4 KB
  __shared__ float2 dtA[SEQLEN];               // 4 KB

  const float dtb = dt_bias[h];
  const float An  = -__expf(A_log[h]);         // A = -exp(A_log)
  for (int t = tid; t < SEQLEN; t += 256) {
    float raw = zx[(size_t)(b * SEQLEN + t) * D_IN_PROJ + (D_INNER + CONV_DIM) + h] + dtb;
    float sp  = (raw > 20.f) ? raw : log1pf(__expf(raw));   // softplus
    dtA[t] = make_float2(sp, __expf(sp * An));
  }

  const float* bcsrc = xbc + (size_t)b * SEQLEN * CONV_DIM + D_INNER + nh * 64;
  const float* xsrc  = xbc + (size_t)b * SEQLEN * CONV_DIM + h * HEADDIM + pq * 16;

  // prologue: stage tile 0 (B/C halves: 32t x 128 floats = 1024 x 16B loads)
  #pragma unroll
  for (int it = 0; it < 4; ++it) {
    const int idx = it * 256 + tid;
    const int t   = idx >> 5;
    const int c   = idx & 31;
    gload_lds16(bcsrc + (size_t)t * CONV_DIM + c * 4 + ((c >= 16) ? 64 : 0),
                &bcs[0][(it * 256 + wave * 64) * 4]);
  }
  if (tid < 128) {
    const float4 xv4 = *(const float4*)(xsrc + (size_t)(tid >> 2) * CONV_DIM + (tid & 3) * 4);
    *(float4*)&xvs[0][(tid >> 2) * 16 + (tid & 3) * 4] = xv4;
  }
  __syncthreads();

  float s0 = 0.f, s1 = 0.f, s2 = 0.f, s3 = 0.f;
  float* ypbase = ypart + (size_t)nh * M_TOKENS * D_INNER
                + (size_t)(b * SEQLEN) * D_INNER + h * HEADDIM + pq * 16;

  for (int k = 0; k < NT; ++k) {
    const int pb = k & 1;
    const int t0 = k * TT;

    // issue next tile's staging (in flight during this tile's compute)
    float4 xv4;
    if (k + 1 < NT) {
      const int t1 = t0 + TT;
      #pragma unroll
      for (int it = 0; it < 4; ++it) {
        const int idx = it * 256 + tid;
        const int t   = idx >> 5;
        const int c   = idx & 31;
        gload_lds16(bcsrc + (size_t)(t1 + t) * CONV_DIM + c * 4 + ((c >= 16) ? 64 : 0),
                    &bcs[pb ^ 1][(it * 256 + wave * 64) * 4]);
      }
      if (tid < 128)
        xv4 = *(const float4*)(xsrc + (size_t)(t1 + (tid >> 2)) * CONV_DIM + (tid & 3) * 4);
    }

    // compute TT steps in groups of 4
    const float* bcb = &bcs[pb][0];
    #pragma unroll
    for (int g = 0; g < TT / 4; ++g) {
      float4 Bv[4], Cv[4];
      float  xv[4];
      float2 da[4];
      #pragma unroll
      for (int j = 0; j < 4; ++j) {
        const float* p = bcb + (g * 4 + j) * 128;
        Bv[j] = *(const float4*)(p + ns * 4);
        Cv[j] = *(const float4*)(p + 64 + ns * 4);
        xv[j] = xvs[pb][(g * 4 + j) * 16 + plocal];
        da[j] = dtA[t0 + g * 4 + j];
      }
      float part[4];
      #pragma unroll
      for (int j = 0; j < 4; ++j) {
        const float cc = da[j].x * xv[j];
        s0 = fmaf(s0, da[j].y, cc * Bv[j].x);
        s1 = fmaf(s1, da[j].y, cc * Bv[j].y);
        s2 = fmaf(s2, da[j].y, cc * Bv[j].z);
        s3 = fmaf(s3, da[j].y, cc * Bv[j].w);
        part[j] = (s0 * Cv[j].x + s1 * Cv[j].y) + (s2 * Cv[j].z + s3 * Cv[j].w);
      }
      #pragma unroll
      for (int o = 1; o < 16; o <<= 1) {   // 4 independent shuffle chains
        part[0] += __shfl_xor(part[0], o);
        part[1] += __shfl_xor(part[1], o);
        part[2] += __shfl_xor(part[2], o);
        part[3] += __shfl_xor(part[3], o);
      }
      if (ns == 0) {
        #pragma unroll
        for (int j = 0; j < 4; ++j)
          yls[pb][(g * 4 + j) * 16 + plocal] = part[j];
      }
    }

    if (k + 1 < NT && tid < 128)
      *(float4*)&xvs[pb ^ 1][(tid >> 2) * 16 + (tid & 3) * 4] = xv4;
    __syncthreads();   // drains staging into [pb^1], yls[pb] writes visible

    // flush this tile's y (next iter writes yls[pb^1] — no extra barrier)
    if (tid < 128) {
      const float4 v = *(const float4*)&yls[pb][(tid >> 2) * 16 + (tid & 3) * 4];
      *(float4*)(ypbase + (size_t)(t0 + (tid >> 2)) * D_INNER + (tid & 3) * 4) = v;
    }
  }
}

// ---------------------------------------------------------------------------
// sum 2 n-half partials + D*x, gate with silu(z), RMSNorm, -> bf16 yn
// ---------------------------------------------------------------------------
__global__ __launch_bounds__(256) void gate_norm(const float* __restrict__ ypart,
                                                 const float* __restrict__ zx,
                                                 const float* __restrict__ xbc,
                                                 const float* __restrict__ Dp,
                                                 const float* __restrict__ nw,
                                                 ushort* __restrict__ yn) {
  const int row = blockIdx.x;
  const int tid = threadIdx.x;
  float vals[8];
  float ss = 0.f;
  #pragma unroll
  for (int i = 0; i < 8; ++i) {
    const int e = tid + i * 256;
    float yv = ypart[(size_t)row * D_INNER + e]
             + ypart[(size_t)(M_TOKENS + row) * D_INNER + e];
    const float xv = xbc[(size_t)row * CONV_DIM + e];
    yv = fmaf(Dp[e >> 6], xv, yv);
    const float z = zx[(size_t)row * D_IN_PROJ + e];
    const float g = z / (1.f + __expf(-z));   // silu(z)
    const float yg = yv * g;
    vals[i] = yg;
    ss = fmaf(yg, yg, ss);
  }
  for (int o = 32; o > 0; o >>= 1) ss += __shfl_down(ss, o);
  __shared__ float wsum[4];
  if ((tid & 63) == 0) wsum[tid >> 6] = ss;
  __syncthreads();
  const float tot = wsum[0] + wsum[1] + wsum[2] + wsum[3];
  const float rms = rsqrtf(tot * (1.f / D_INNER) + EPS);
  #pragma unroll
  for (int i = 0; i < 8; ++i) {
    const int e = tid + i * 256;
    yn[(size_t)row * D_INNER + e] = f2bf(vals[i] * rms * nw[e]);
  }
}

// ---------------------------------------------------------------------------
extern "C" void kernel_launch(void* const* d_in, const int* in_sizes, int n_in,
                              void* d_out, int out_size, void* d_ws, size_t ws_size,
                              hipStream_t stream) {
  const float* u       = (const float*)d_in[0];
  const float* W_in    = (const float*)d_in[1];
  const float* conv_w  = (const float*)d_in[2];
  const float* conv_b  = (const float*)d_in[3];
  const float* dt_bias = (const float*)d_in[4];
  const float* A_log   = (const float*)d_in[5];
  const float* D_par   = (const float*)d_in[6];
  const float* norm_w  = (const float*)d_in[7];
  const float* W_out   = (const float*)d_in[8];
  float* out = (float*)d_out;

  char* ws = (char*)d_ws;
  // ws layout (bytes), 16B-aligned:
  //   zx      : fp32 [1024][4384]     = 17,956,864  @ 0
  //   xbc     : fp32 [1024][2304]     =  9,437,184  @ 17,956,864
  //   ypart   : fp32 [2][1024][2048]  = 16,777,216  @ 27,394,048
  //   yn      : bf16 [1024][2048]     =  4,194,304  @ 44,171,264
  //   u_bf    : bf16 [1024][1024]     =  2,097,152  @ 48,365,568
  //   Win_bf  : bf16 [4384][1024]     =  8,978,432  @ 50,462,720
  //   Wout_bf : bf16 [1024][2048]     =  4,194,304  @ 59,441,152  (end 63.6MB)
  // NOTE: gemm_tile<128,128,1> reads Bt rows up to 4480 -> spills ~196KB past
  // Win_bf into Wout_bf (finite bf16, results masked on store). Keep adjacent.
  float*  zx      = (float*)ws;
  float*  xbc     = (float*)(ws + 17956864);
  float*  ypart   = (float*)(ws + 27394048);
  ushort* yn      = (ushort*)(ws + 44171264);
  ushort* u_bf    = (ushort*)(ws + 48365568);
  ushort* Win_bf  = (ushort*)(ws + 50462720);
  ushort* Wout_bf = (ushort*)(ws + 59441152);

  cvt_f32_bf16<<<(M_TOKENS * D_MODEL) / (256 * 8), 256, 0, stream>>>(u, u_bf, M_TOKENS * D_MODEL);
  cvt_f32_bf16<<<(D_IN_PROJ * D_MODEL) / (256 * 8), 256, 0, stream>>>(W_in, Win_bf, D_IN_PROJ * D_MODEL);
  cvt_f32_bf16<<<(D_MODEL * D_INNER) / (256 * 8), 256, 0, stream>>>(W_out, Wout_bf, D_MODEL * D_INNER);

  // in_proj: M=1024, N=4384 (padded grid to 4480), K=1024
  gemm_tile<128, 128, 1><<<dim3(NPROJ_PAD / 128, M_TOKENS / 128), 256, 0, stream>>>(
      u_bf, Win_bf, zx, D_IN_PROJ, D_MODEL, D_IN_PROJ);
  conv_silu<<<(M_TOKENS * CONV_DIM) / 256, 256, 0, stream>>>(zx, conv_w, conv_b, xbc);
  scan<<<BATCH * NHEADS * 4 * 2, 256, 0, stream>>>(zx, xbc, dt_bias, A_log, ypart);
  gate_norm<<<M_TOKENS, 256, 0, stream>>>(ypart, zx, xbc, D_par, norm_w, yn);
  // out_proj: M=1024, N=1024, K=2048
  gemm_tile<64, 64, 0><<<dim3(D_MODEL / 64, M_TOKENS / 64), 256, 0, stream>>>(
      yn, Wout_bf, out, D_MODEL, D_INNER, D_MODEL);
}

// Round 5
// 211.695 us; speedup vs baseline: 2.3028x; 1.1987x over previous
//
#include <hip/hip_runtime.h>
#include <hip/hip_bf16.h>

#define D_MODEL   1024
#define D_STATE   128
#define D_INNER   2048
#define NHEADS    32
#define HEADDIM   64
#define D_IN_PROJ 4384   // 2*D_INNER + 2*D_STATE + NHEADS
#define NPROJ_PAD 4480   // 35*128 (GEMM tile padding; stores masked to 4384)
#define CONV_DIM  2304   // D_INNER + 2*D_STATE
#define BATCH     2
#define SEQLEN    512
#define M_TOKENS  (BATCH*SEQLEN)   // 1024
#define EPS       1e-5f
#define LC        64               // SSD chunk length
#define NCH       (SEQLEN/LC)      // 8 chunks

typedef __bf16 bf16x8 __attribute__((ext_vector_type(8)));
typedef float  f32x4  __attribute__((ext_vector_type(4)));

__device__ __forceinline__ ushort f2bf(float f) {
  union { float f; unsigned int i; } v; v.f = f;
  unsigned int x = v.i;
  return (ushort)((x + 0x7fffu + ((x >> 16) & 1u)) >> 16);
}
__device__ __forceinline__ float bf2f(ushort u) {
  union { unsigned int i; float f; } v; v.i = ((unsigned int)u) << 16; return v.f;
}

__device__ __forceinline__ void gload_lds16u(const ushort* g, ushort* l) {
  __builtin_amdgcn_global_load_lds(
      (const __attribute__((address_space(1))) void*)g,
      (__attribute__((address_space(3))) void*)l, 16, 0, 0);
}

// ---------------------------------------------------------------------------
// fp32 -> bf16 conversion, 8 elems/thread
// ---------------------------------------------------------------------------
__global__ __launch_bounds__(256) void cvt_f32_bf16(const float* __restrict__ src,
                                                    ushort* __restrict__ dst, int n) {
  const int i = (blockIdx.x * 256 + threadIdx.x) * 8;
  if (i >= n) return;
  const float4 a = *(const float4*)(src + i);
  const float4 b = *(const float4*)(src + i + 4);
  uint4 v;
  v.x = (unsigned)f2bf(a.x) | ((unsigned)f2bf(a.y) << 16);
  v.y = (unsigned)f2bf(a.z) | ((unsigned)f2bf(a.w) << 16);
  v.z = (unsigned)f2bf(b.x) | ((unsigned)f2bf(b.y) << 16);
  v.w = (unsigned)f2bf(b.z) | ((unsigned)f2bf(b.w) << 16);
  *(uint4*)(dst + i) = v;
}

// ---------------------------------------------------------------------------
// m97-style tiled GEMM (unchanged from round 3)
// ---------------------------------------------------------------------------
template <int BM, int BN, int MASK_N>
__global__ __launch_bounds__(256) void gemm_tile(const ushort* __restrict__ A,
                                                 const ushort* __restrict__ Bt,
                                                 float* __restrict__ C,
                                                 int Nreal, int K, int ldc) {
  constexpr int WM = BM / 2, WN = BN / 2, FM = WM / 16, FN = WN / 16;
  constexpr int LA = BM * 4 / 256, LB = BN * 4 / 256;
  __shared__ ushort As[BM * 32];
  __shared__ ushort Bs[BN * 32];
  const int tid = threadIdx.x, lane = tid & 63, wave = tid >> 6;
  const int r16 = lane & 15, q = lane >> 4;
  const int wm = wave & 1, wn = wave >> 1;
  const int m0 = blockIdx.y * BM, n0 = blockIdx.x * BN;

  f32x4 acc[FM][FN] = {};

  for (int k0 = 0; k0 < K; k0 += 32) {
    __syncthreads();
    #pragma unroll
    for (int it = 0; it < LA; ++it) {
      const int idx = it * 256 + tid;
      gload_lds16u(A + (size_t)(m0 + (idx >> 2)) * K + k0 + (idx & 3) * 8,
                   As + (it * 256 + wave * 64) * 8);
    }
    #pragma unroll
    for (int it = 0; it < LB; ++it) {
      const int idx = it * 256 + tid;
      gload_lds16u(Bt + (size_t)(n0 + (idx >> 2)) * K + k0 + (idx & 3) * 8,
                   Bs + (it * 256 + wave * 64) * 8);
    }
    __syncthreads();

    bf16x8 af[FM], bfr[FN];
    #pragma unroll
    for (int i = 0; i < FM; ++i)
      af[i] = *(const bf16x8*)(const void*)(As + (wm * WM + i * 16 + r16) * 32 + q * 8);
    #pragma unroll
    for (int j = 0; j < FN; ++j)
      bfr[j] = *(const bf16x8*)(const void*)(Bs + (wn * WN + j * 16 + r16) * 32 + q * 8);
    #pragma unroll
    for (int i = 0; i < FM; ++i)
      #pragma unroll
      for (int j = 0; j < FN; ++j)
        acc[i][j] = __builtin_amdgcn_mfma_f32_16x16x32_bf16(af[i], bfr[j], acc[i][j], 0, 0, 0);
  }

  #pragma unroll
  for (int i = 0; i < FM; ++i) {
    const int row = m0 + wm * WM + i * 16 + q * 4;
    #pragma unroll
    for (int j = 0; j < FN; ++j) {
      const int col = n0 + wn * WN + j * 16 + r16;
      if (!MASK_N || col < Nreal) {
        #pragma unroll
        for (int r = 0; r < 4; ++r)
          C[(size_t)(row + r) * ldc + col] = acc[i][j][r];
      }
    }
  }
}

// ---------------------------------------------------------------------------
// causal depthwise conv (k=4) + bias + SiLU; also emits bf16 copy of B|C cols
// ---------------------------------------------------------------------------
__global__ __launch_bounds__(256) void conv_silu(const float* __restrict__ zx,
                                                 const float* __restrict__ cw,
                                                 const float* __restrict__ cb,
                                                 float* __restrict__ xbc,
                                                 ushort* __restrict__ BCbf) {
  const int idx = blockIdx.x * 256 + threadIdx.x;     // over M_TOKENS*CONV_DIM
  const int c   = idx % CONV_DIM;
  const int bt  = idx / CONV_DIM;
  const int t   = bt % SEQLEN;

  float acc = cb[c];
  #pragma unroll
  for (int k = 0; k < 4; ++k) {
    const int tt = t - 3 + k;
    if (tt >= 0) {
      acc += zx[(size_t)(bt - 3 + k) * D_IN_PROJ + D_INNER + c] * cw[c * 4 + k];
    }
  }
  const float s = acc / (1.f + __expf(-acc));   // silu
  xbc[idx] = s;
  if (c >= D_INNER) BCbf[(size_t)bt * 256 + (c - D_INNER)] = f2bf(s);
}

// ---------------------------------------------------------------------------
// K0: dt = softplus(raw+bias); csum = chunk-local inclusive prefix of dt*A.
// grid 64 = (b,h); block 512 (wave == one 64-chunk).
// ---------------------------------------------------------------------------
__global__ __launch_bounds__(512) void dtcsum(const float* __restrict__ zx,
                                              const float* __restrict__ dt_bias,
                                              const float* __restrict__ A_log,
                                              float* __restrict__ dts,
                                              float* __restrict__ csum) {
  const int bh = blockIdx.x;
  const int b = bh >> 5, h = bh & 31;
  const int t = threadIdx.x;
  const float raw = zx[(size_t)(b * SEQLEN + t) * D_IN_PROJ + (D_INNER + CONV_DIM) + h]
                  + dt_bias[h];
  const float sp = (raw > 20.f) ? raw : log1pf(__expf(raw));
  const float An = -__expf(A_log[h]);
  float x = sp * An;
  #pragma unroll
  for (int off = 1; off < 64; off <<= 1) {
    const float v = __shfl_up(x, off);
    if ((t & 63) >= off) x += v;
  }
  dts[(size_t)bh * SEQLEN + t]  = sp;
  csum[(size_t)bh * SEQLEN + t] = x;
}

// ---------------------------------------------------------------------------
// K1a: G[t][s] = C_t · B_s  (64x64, K=128) per (b,chunk). h-independent.
// grid 16 = b*8+c; 256 thr; direct-from-global bf16 frags.
// ---------------------------------------------------------------------------
__global__ __launch_bounds__(256) void chunk_G(const ushort* __restrict__ BCbf,
                                               float* __restrict__ G) {
  const int blk = blockIdx.x;
  const int b = blk >> 3, c = blk & 7;
  const int tid = threadIdx.x, lane = tid & 63, wave = tid >> 6;
  const int r16 = lane & 15, q = lane >> 4;
  const ushort* Cp = BCbf + (size_t)(b * SEQLEN + c * LC + wave * 16 + r16) * 256 + 128 + q * 8;
  const ushort* Bp = BCbf + (size_t)(b * SEQLEN + c * LC + r16) * 256 + q * 8;
  f32x4 acc[4] = {};
  #pragma unroll
  for (int kk = 0; kk < 4; ++kk) {
    const bf16x8 a = *(const bf16x8*)(const void*)(Cp + kk * 32);
    #pragma unroll
    for (int j = 0; j < 4; ++j) {
      const bf16x8 bb = *(const bf16x8*)(const void*)(Bp + (size_t)j * 16 * 256 + kk * 32);
      acc[j] = __builtin_amdgcn_mfma_f32_16x16x32_bf16(a, bb, acc[j], 0, 0, 0);
    }
  }
  float* Gp = G + (size_t)blk * 4096;
  #pragma unroll
  for (int j = 0; j < 4; ++j)
    #pragma unroll
    for (int r = 0; r < 4; ++r)
      Gp[(wave * 16 + q * 4 + r) * 64 + j * 16 + r16] = acc[j][r];
}

// ---------------------------------------------------------------------------
// K1b: per (b,h,c): M = G∘L (L[t][s] = dt_s*exp(cs[t]-cs[s]), s<=t);
//   Yi = M·X (64x64,K=64); dS = Bw·X (128x64,K=64), Bw[n][s]=B_s[n]*w_s,
//   w_s = dt_s*exp(cs[63]-cs[s]).  X[s][p] = x. grid 512; 256 thr.
// LDS ld = 72 shorts (144B rows -> 2-way bank alias on b128, free).
// ---------------------------------------------------------------------------
__global__ __launch_bounds__(256) void chunk_intra(const float* __restrict__ xbc,
                                                   const float* __restrict__ Gg,
                                                   const float* __restrict__ dts,
                                                   const float* __restrict__ csum,
                                                   float* __restrict__ Yi,
                                                   ushort* __restrict__ dS) {
  const int blk = blockIdx.x;
  const int c = blk & 7, h = (blk >> 3) & 31, b = blk >> 8;
  const int bh = b * 32 + h;
  const int tid = threadIdx.x, lane = tid & 63, wave = tid >> 6;
  const int r16 = lane & 15, q = lane >> 4;

  __shared__ ushort Ml[64 * 72];
  __shared__ ushort Xt[64 * 72];
  __shared__ ushort Bw[128 * 72];
  __shared__ float dtl[LC], csl[LC];

  if (tid < LC) {
    dtl[tid] = dts[(size_t)bh * SEQLEN + c * LC + tid];
    csl[tid] = csum[(size_t)bh * SEQLEN + c * LC + tid];
  }
  __syncthreads();
  const float cs63 = csl[LC - 1];

  const float* Gp = Gg + (size_t)(b * 8 + c) * 4096;
  #pragma unroll
  for (int i = 0; i < 16; ++i) {
    const int idx = i * 256 + tid;
    const int t = idx >> 6, s = idx & 63;
    const float v = (s <= t) ? Gp[idx] * dtl[s] * __expf(csl[t] - csl[s]) : 0.f;
    Ml[t * 72 + s] = f2bf(v);
  }
  const float* xb = xbc + (size_t)(b * SEQLEN + c * LC) * CONV_DIM + h * HEADDIM;
  #pragma unroll
  for (int i = 0; i < 16; ++i) {
    const int idx = i * 256 + tid;
    const int s = idx >> 6, p = idx & 63;
    Xt[p * 72 + s] = f2bf(xb[(size_t)s * CONV_DIM + p]);
  }
  const float* Bb = xbc + (size_t)(b * SEQLEN + c * LC) * CONV_DIM + D_INNER;
  #pragma unroll
  for (int i = 0; i < 32; ++i) {
    const int idx = i * 256 + tid;
    const int s = idx >> 7, n = idx & 127;
    const float w = dtl[s] * __expf(cs63 - csl[s]);
    Bw[n * 72 + s] = f2bf(Bb[(size_t)s * CONV_DIM + n] * w);
  }
  __syncthreads();

  f32x4 accY[4] = {};
  f32x4 accS[2][4] = {};
  #pragma unroll
  for (int kk = 0; kk < 2; ++kk) {
    const bf16x8 am = *(const bf16x8*)(const void*)(Ml + (wave * 16 + r16) * 72 + kk * 32 + q * 8);
    const bf16x8 a0 = *(const bf16x8*)(const void*)(Bw + (wave * 32 + r16) * 72 + kk * 32 + q * 8);
    const bf16x8 a1 = *(const bf16x8*)(const void*)(Bw + (wave * 32 + 16 + r16) * 72 + kk * 32 + q * 8);
    #pragma unroll
    for (int j = 0; j < 4; ++j) {
      const bf16x8 bx = *(const bf16x8*)(const void*)(Xt + (j * 16 + r16) * 72 + kk * 32 + q * 8);
      accY[j]    = __builtin_amdgcn_mfma_f32_16x16x32_bf16(am, bx, accY[j], 0, 0, 0);
      accS[0][j] = __builtin_amdgcn_mfma_f32_16x16x32_bf16(a0, bx, accS[0][j], 0, 0, 0);
      accS[1][j] = __builtin_amdgcn_mfma_f32_16x16x32_bf16(a1, bx, accS[1][j], 0, 0, 0);
    }
  }

  float* Yp = Yi + (size_t)blk * 4096;
  #pragma unroll
  for (int j = 0; j < 4; ++j)
    #pragma unroll
    for (int r = 0; r < 4; ++r)
      Yp[(wave * 16 + q * 4 + r) * 64 + j * 16 + r16] = accY[j][r];

  ushort* Sp = dS + (size_t)blk * 8192;
  #pragma unroll
  for (int u = 0; u < 2; ++u)
    #pragma unroll
    for (int j = 0; j < 4; ++j)
      #pragma unroll
      for (int r = 0; r < 4; ++r)
        Sp[(wave * 32 + u * 16 + q * 4 + r) * 64 + j * 16 + r16] = f2bf(accS[u][j][r]);
}

// ---------------------------------------------------------------------------
// K2: sequential chunk-state carry. grid 64 = (b,h); 256 thr.
// S(128n x 64p) fp32 in regs (32/thread). Per c: emit St[p][n] (bf16, start
// state for chunk c), then S = exp(csum_end_c)*S + dS_c.
// ---------------------------------------------------------------------------
__global__ __launch_bounds__(256) void chunk_state(const ushort* __restrict__ dS,
                                                   const float* __restrict__ csum,
                                                   ushort* __restrict__ St) {
  const int bh = blockIdx.x;
  const int tid = threadIdx.x;
  const int p = tid & 63, n0 = (tid >> 6) * 32;
  float S[32] = {};
  for (int c = 0; c < NCH; ++c) {
    const size_t base = ((size_t)bh * 8 + c) * 8192;
    uint4 pk[4];
    unsigned* pw = (unsigned*)pk;
    #pragma unroll
    for (int j = 0; j < 16; ++j)
      pw[j] = (unsigned)f2bf(S[2 * j]) | ((unsigned)f2bf(S[2 * j + 1]) << 16);
    uint4* dst = (uint4*)(St + base + (size_t)p * 128 + n0);
    #pragma unroll
    for (int j = 0; j < 4; ++j) dst[j] = pk[j];
    const float e = __expf(csum[(size_t)bh * SEQLEN + c * LC + (LC - 1)]);
    #pragma unroll
    for (int j = 0; j < 32; ++j) {
      const float d = bf2f(dS[base + (size_t)(n0 + j) * 64 + p]);
      S[j] = S[j] * e + d;
    }
  }
}

// ---------------------------------------------------------------------------
// K3: Y[t][p] = exp(cs[t]) * (C_t · S_start) + Yi[t][p] + D_h * x[t][p]
// grid 512 (b,h,c); GEMM 64x64 K=128 direct-from-global.
// ---------------------------------------------------------------------------
__global__ __launch_bounds__(256) void chunk_inter(const ushort* __restrict__ BCbf,
                                                   const ushort* __restrict__ St,
                                                   const float* __restrict__ Yi,
                                                   const float* __restrict__ xbc,
                                                   const float* __restrict__ csum,
                                                   const float* __restrict__ Dp,
                                                   float* __restrict__ y) {
  const int blk = blockIdx.x;
  const int c = blk & 7, h = (blk >> 3) & 31, b = blk >> 8;
  const int bh = b * 32 + h;
  const int tid = threadIdx.x, lane = tid & 63, wave = tid >> 6;
  const int r16 = lane & 15, q = lane >> 4;

  const ushort* Cp = BCbf + (size_t)(b * SEQLEN + c * LC + wave * 16 + r16) * 256 + 128 + q * 8;
  const ushort* Sp = St + (size_t)blk * 8192 + (size_t)r16 * 128 + q * 8;
  f32x4 acc[4] = {};
  #pragma unroll
  for (int kk = 0; kk < 4; ++kk) {
    const bf16x8 a = *(const bf16x8*)(const void*)(Cp + kk * 32);
    #pragma unroll
    for (int j = 0; j < 4; ++j) {
      const bf16x8 bb = *(const bf16x8*)(const void*)(Sp + (size_t)j * 16 * 128 + kk * 32);
      acc[j] = __builtin_amdgcn_mfma_f32_16x16x32_bf16(a, bb, acc[j], 0, 0, 0);
    }
  }

  const float Dh = Dp[h];
  const float* Yp = Yi + (size_t)blk * 4096;
  float sc[4];
  #pragma unroll
  for (int r = 0; r < 4; ++r)
    sc[r] = __expf(csum[(size_t)bh * SEQLEN + c * LC + wave * 16 + q * 4 + r]);
  #pragma unroll
  for (int j = 0; j < 4; ++j) {
    const int col = j * 16 + r16;
    #pragma unroll
    for (int r = 0; r < 4; ++r) {
      const int t = wave * 16 + q * 4 + r;
      const size_t row = (size_t)(b * SEQLEN + c * LC + t);
      const float xv = xbc[row * CONV_DIM + h * HEADDIM + col];
      y[row * D_INNER + h * HEADDIM + col] =
          acc[j][r] * sc[r] + Yp[t * 64 + col] + Dh * xv;
    }
  }
}

// ---------------------------------------------------------------------------
// y + gate silu(z), RMSNorm -> bf16 yn
// ---------------------------------------------------------------------------
__global__ __launch_bounds__(256) void gate_norm(const float* __restrict__ y,
                                                 const float* __restrict__ zx,
                                                 const float* __restrict__ nw,
                                                 ushort* __restrict__ yn) {
  const int row = blockIdx.x;
  const int tid = threadIdx.x;
  float vals[8];
  float ss = 0.f;
  #pragma unroll
  for (int i = 0; i < 8; ++i) {
    const int e = tid + i * 256;
    const float yv = y[(size_t)row * D_INNER + e];
    const float z = zx[(size_t)row * D_IN_PROJ + e];
    const float g = z / (1.f + __expf(-z));   // silu(z)
    const float yg = yv * g;
    vals[i] = yg;
    ss = fmaf(yg, yg, ss);
  }
  for (int o = 32; o > 0; o >>= 1) ss += __shfl_down(ss, o);
  __shared__ float wsum[4];
  if ((tid & 63) == 0) wsum[tid >> 6] = ss;
  __syncthreads();
  const float tot = wsum[0] + wsum[1] + wsum[2] + wsum[3];
  const float rms = rsqrtf(tot * (1.f / D_INNER) + EPS);
  #pragma unroll
  for (int i = 0; i < 8; ++i) {
    const int e = tid + i * 256;
    yn[(size_t)row * D_INNER + e] = f2bf(vals[i] * rms * nw[e]);
  }
}

// ---------------------------------------------------------------------------
extern "C" void kernel_launch(void* const* d_in, const int* in_sizes, int n_in,
                              void* d_out, int out_size, void* d_ws, size_t ws_size,
                              hipStream_t stream) {
  const float* u       = (const float*)d_in[0];
  const float* W_in    = (const float*)d_in[1];
  const float* conv_w  = (const float*)d_in[2];
  const float* conv_b  = (const float*)d_in[3];
  const float* dt_bias = (const float*)d_in[4];
  const float* A_log   = (const float*)d_in[5];
  const float* D_par   = (const float*)d_in[6];
  const float* norm_w  = (const float*)d_in[7];
  const float* W_out   = (const float*)d_in[8];
  float* out = (float*)d_out;

  char* ws = (char*)d_ws;
  // ws layout (bytes), 16B-aligned:
  //   zx      fp32 [1024][4384]      17,956,864  @ 0
  //   xbc     fp32 [1024][2304]       9,437,184  @ 17,956,864
  //   y       fp32 [1024][2048]       8,388,608  @ 27,394,048
  //   yn      bf16 [1024][2048]       4,194,304  @ 35,782,656
  //   u_bf    bf16 [1024][1024]       2,097,152  @ 39,976,960   (dead after in_proj)
  //   Win_bf  bf16 [4384][1024]       8,978,432  @ 42,074,112   (dead after in_proj)
  //   Yi      fp32 [512][64][64]      8,388,608  @ 39,976,960   ALIAS of u_bf+Win_bf
  //   Wout_bf bf16 [1024][2048]       4,194,304  @ 51,052,544
  //   BC_bf   bf16 [1024][256]          524,288  @ 55,246,848
  //   dts     fp32 [64][512]            131,072  @ 55,771,136
  //   csum    fp32 [64][512]            131,072  @ 55,902,208
  //   G       fp32 [16][64][64]         262,144  @ 56,033,280
  //   dS      bf16 [512][128][64]     8,388,608  @ 56,295,424
  //   St      bf16 [512][64][128]     8,388,608  @ 64,684,032   (end 73,072,640)
  // in_proj reads Bt rows to 4480 -> spills past Win_bf into Wout_bf (finite,
  // masked on store). Keep Wout_bf adjacent after Win_bf region.
  float*  zx      = (float*)ws;
  float*  xbc     = (float*)(ws + 17956864);
  float*  yb      = (float*)(ws + 27394048);
  ushort* yn      = (ushort*)(ws + 35782656);
  ushort* u_bf    = (ushort*)(ws + 39976960);
  ushort* Win_bf  = (ushort*)(ws + 42074112);
  float*  Yi      = (float*)(ws + 39976960);
  ushort* Wout_bf = (ushort*)(ws + 51052544);
  ushort* BC_bf   = (ushort*)(ws + 55246848);
  float*  dts     = (float*)(ws + 55771136);
  float*  csum    = (float*)(ws + 55902208);
  float*  G       = (float*)(ws + 56033280);
  ushort* dS      = (ushort*)(ws + 56295424);
  ushort* St      = (ushort*)(ws + 64684032);

  cvt_f32_bf16<<<(M_TOKENS * D_MODEL) / (256 * 8), 256, 0, stream>>>(u, u_bf, M_TOKENS * D_MODEL);
  cvt_f32_bf16<<<(D_IN_PROJ * D_MODEL) / (256 * 8), 256, 0, stream>>>(W_in, Win_bf, D_IN_PROJ * D_MODEL);
  cvt_f32_bf16<<<(D_MODEL * D_INNER) / (256 * 8), 256, 0, stream>>>(W_out, Wout_bf, D_MODEL * D_INNER);

  // in_proj: M=1024, N=4384 (grid padded to 4480), K=1024
  gemm_tile<128, 128, 1><<<dim3(NPROJ_PAD / 128, M_TOKENS / 128), 256, 0, stream>>>(
      u_bf, Win_bf, zx, D_IN_PROJ, D_MODEL, D_IN_PROJ);
  conv_silu<<<(M_TOKENS * CONV_DIM) / 256, 256, 0, stream>>>(zx, conv_w, conv_b, xbc, BC_bf);

  dtcsum<<<BATCH * NHEADS, 512, 0, stream>>>(zx, dt_bias, A_log, dts, csum);
  chunk_G<<<BATCH * NCH, 256, 0, stream>>>(BC_bf, G);
  chunk_intra<<<BATCH * NHEADS * NCH, 256, 0, stream>>>(xbc, G, dts, csum, Yi, dS);
  chunk_state<<<BATCH * NHEADS, 256, 0, stream>>>(dS, csum, St);
  chunk_inter<<<BATCH * NHEADS * NCH, 256, 0, stream>>>(BC_bf, St, Yi, xbc, csum, D_par, yb);

  gate_norm<<<M_TOKENS, 256, 0, stream>>>(yb, zx, norm_w, yn);
  // out_proj: M=1024, N=1024, K=2048
  gemm_tile<64, 64, 0><<<dim3(D_MODEL / 64, M_TOKENS / 64), 256, 0, stream>>>(
      yn, Wout_bf, out, D_MODEL, D_INNER, D_MODEL);
}

// Round 6
// 194.360 us; speedup vs baseline: 2.5082x; 1.0892x over previous
//
#include <hip/hip_runtime.h>
#include <hip/hip_bf16.h>

#define D_MODEL   1024
#define D_STATE   128
#define D_INNER   2048
#define NHEADS    32
#define HEADDIM   64
#define D_IN_PROJ 4384   // 2*D_INNER + 2*D_STATE + NHEADS
#define NPROJ_PAD 4480   // GEMM tile padding; stores masked to 4384
#define CONV_DIM  2304   // D_INNER + 2*D_STATE
#define BATCH     2
#define SEQLEN    512
#define M_TOKENS  (BATCH*SEQLEN)   // 1024
#define EPS       1e-5f
#define LC        64               // SSD chunk length
#define NCH       (SEQLEN/LC)      // 8 chunks

typedef __bf16 bf16x8 __attribute__((ext_vector_type(8)));
typedef float  f32x4  __attribute__((ext_vector_type(4)));

__device__ __forceinline__ ushort f2bf(float f) {
  union { float f; unsigned int i; } v; v.f = f;
  unsigned int x = v.i;
  return (ushort)((x + 0x7fffu + ((x >> 16) & 1u)) >> 16);
}
__device__ __forceinline__ float bf2f(ushort u) {
  union { unsigned int i; float f; } v; v.i = ((unsigned int)u) << 16; return v.f;
}

__device__ __forceinline__ void gload_lds16u(const ushort* g, ushort* l) {
  __builtin_amdgcn_global_load_lds(
      (const __attribute__((address_space(1))) void*)g,
      (__attribute__((address_space(3))) void*)l, 16, 0, 0);
}

// ---------------------------------------------------------------------------
// fused fp32->bf16 conversion of u, W_in, W_out (one launch), 8 elems/thread
// ---------------------------------------------------------------------------
__device__ __forceinline__ void cvt8(const float* __restrict__ s,
                                     ushort* __restrict__ d, int i) {
  const float4 a = *(const float4*)(s + i);
  const float4 b = *(const float4*)(s + i + 4);
  uint4 v;
  v.x = (unsigned)f2bf(a.x) | ((unsigned)f2bf(a.y) << 16);
  v.y = (unsigned)f2bf(a.z) | ((unsigned)f2bf(a.w) << 16);
  v.z = (unsigned)f2bf(b.x) | ((unsigned)f2bf(b.y) << 16);
  v.w = (unsigned)f2bf(b.z) | ((unsigned)f2bf(b.w) << 16);
  *(uint4*)(d + i) = v;
}
__global__ __launch_bounds__(256) void cvt3(const float* __restrict__ s0, ushort* __restrict__ d0, int n0,
                                            const float* __restrict__ s1, ushort* __restrict__ d1, int n1,
                                            const float* __restrict__ s2, ushort* __restrict__ d2, int n2) {
  const int i = (blockIdx.x * 256 + threadIdx.x) * 8;
  if (i < n0)                cvt8(s0, d0, i);
  else if (i < n0 + n1)      cvt8(s1, d1, i - n0);
  else if (i < n0 + n1 + n2) cvt8(s2, d2, i - n0 - n1);
}

// ---------------------------------------------------------------------------
// m97-style tiled GEMM (BM x BN, BK=32), 256 thr / 2x2 waves.
// ---------------------------------------------------------------------------
template <int BM, int BN, int MASK_N>
__global__ __launch_bounds__(256) void gemm_tile(const ushort* __restrict__ A,
                                                 const ushort* __restrict__ Bt,
                                                 float* __restrict__ C,
                                                 int Nreal, int K, int ldc) {
  constexpr int WM = BM / 2, WN = BN / 2, FM = WM / 16, FN = WN / 16;
  constexpr int LA = BM * 4 / 256, LB = BN * 4 / 256;
  __shared__ ushort As[BM * 32];
  __shared__ ushort Bs[BN * 32];
  const int tid = threadIdx.x, lane = tid & 63, wave = tid >> 6;
  const int r16 = lane & 15, q = lane >> 4;
  const int wm = wave & 1, wn = wave >> 1;
  const int m0 = blockIdx.y * BM, n0 = blockIdx.x * BN;

  f32x4 acc[FM][FN] = {};

  for (int k0 = 0; k0 < K; k0 += 32) {
    __syncthreads();
    #pragma unroll
    for (int it = 0; it < LA; ++it) {
      const int idx = it * 256 + tid;
      gload_lds16u(A + (size_t)(m0 + (idx >> 2)) * K + k0 + (idx & 3) * 8,
                   As + (it * 256 + wave * 64) * 8);
    }
    #pragma unroll
    for (int it = 0; it < LB; ++it) {
      const int idx = it * 256 + tid;
      gload_lds16u(Bt + (size_t)(n0 + (idx >> 2)) * K + k0 + (idx & 3) * 8,
                   Bs + (it * 256 + wave * 64) * 8);
    }
    __syncthreads();

    bf16x8 af[FM], bfr[FN];
    #pragma unroll
    for (int i = 0; i < FM; ++i)
      af[i] = *(const bf16x8*)(const void*)(As + (wm * WM + i * 16 + r16) * 32 + q * 8);
    #pragma unroll
    for (int j = 0; j < FN; ++j)
      bfr[j] = *(const bf16x8*)(const void*)(Bs + (wn * WN + j * 16 + r16) * 32 + q * 8);
    #pragma unroll
    for (int i = 0; i < FM; ++i)
      #pragma unroll
      for (int j = 0; j < FN; ++j)
        acc[i][j] = __builtin_amdgcn_mfma_f32_16x16x32_bf16(af[i], bfr[j], acc[i][j], 0, 0, 0);
  }

  #pragma unroll
  for (int i = 0; i < FM; ++i) {
    const int row = m0 + wm * WM + i * 16 + q * 4;
    #pragma unroll
    for (int j = 0; j < FN; ++j) {
      const int col = n0 + wn * WN + j * 16 + r16;
      if (!MASK_N || col < Nreal) {
        #pragma unroll
        for (int r = 0; r < 4; ++r)
          C[(size_t)(row + r) * ldc + col] = acc[i][j][r];
      }
    }
  }
}

// ---------------------------------------------------------------------------
// out_proj split-K GEMM: 64x64 tile, K split in 2 halves (blockIdx.z),
// epilogue accumulates into zero-initialized C via unsafeAtomicAdd.
// ---------------------------------------------------------------------------
__global__ __launch_bounds__(256) void gemm_sk(const ushort* __restrict__ A,
                                               const ushort* __restrict__ Bt,
                                               float* __restrict__ C,
                                               int Khalf, int ldab, int ldc) {
  __shared__ ushort As[64 * 32];
  __shared__ ushort Bs[64 * 32];
  const int tid = threadIdx.x, lane = tid & 63, wave = tid >> 6;
  const int r16 = lane & 15, q = lane >> 4;
  const int wm = wave & 1, wn = wave >> 1;
  const int m0 = blockIdx.y * 64, n0 = blockIdx.x * 64;
  const int kb = blockIdx.z * Khalf;

  f32x4 acc[2][2] = {};
  for (int k0 = 0; k0 < Khalf; k0 += 32) {
    __syncthreads();
    gload_lds16u(A + (size_t)(m0 + (tid >> 2)) * ldab + kb + k0 + (tid & 3) * 8,
                 As + (tid & ~63) * 8 /* wave*64*8 */);
    gload_lds16u(Bt + (size_t)(n0 + (tid >> 2)) * ldab + kb + k0 + (tid & 3) * 8,
                 Bs + (tid & ~63) * 8);
    __syncthreads();

    bf16x8 af[2], bfr[2];
    #pragma unroll
    for (int i = 0; i < 2; ++i)
      af[i] = *(const bf16x8*)(const void*)(As + (wm * 32 + i * 16 + r16) * 32 + q * 8);
    #pragma unroll
    for (int j = 0; j < 2; ++j)
      bfr[j] = *(const bf16x8*)(const void*)(Bs + (wn * 32 + j * 16 + r16) * 32 + q * 8);
    #pragma unroll
    for (int i = 0; i < 2; ++i)
      #pragma unroll
      for (int j = 0; j < 2; ++j)
        acc[i][j] = __builtin_amdgcn_mfma_f32_16x16x32_bf16(af[i], bfr[j], acc[i][j], 0, 0, 0);
  }

  #pragma unroll
  for (int i = 0; i < 2; ++i) {
    const int row = m0 + wm * 32 + i * 16 + q * 4;
    #pragma unroll
    for (int j = 0; j < 2; ++j) {
      const int col = n0 + wn * 32 + j * 16 + r16;
      #pragma unroll
      for (int r = 0; r < 4; ++r)
        unsafeAtomicAdd(&C[(size_t)(row + r) * ldc + col], acc[i][j][r]);
    }
  }
}

// ---------------------------------------------------------------------------
// causal depthwise conv (k=4) + bias + SiLU; also emits bf16 copy of B|C cols
// ---------------------------------------------------------------------------
__global__ __launch_bounds__(256) void conv_silu(const float* __restrict__ zx,
                                                 const float* __restrict__ cw,
                                                 const float* __restrict__ cb,
                                                 float* __restrict__ xbc,
                                                 ushort* __restrict__ BCbf) {
  const int idx = blockIdx.x * 256 + threadIdx.x;     // over M_TOKENS*CONV_DIM
  const int c   = idx % CONV_DIM;
  const int bt  = idx / CONV_DIM;
  const int t   = bt % SEQLEN;

  float acc = cb[c];
  #pragma unroll
  for (int k = 0; k < 4; ++k) {
    const int tt = t - 3 + k;
    if (tt >= 0) {
      acc += zx[(size_t)(bt - 3 + k) * D_IN_PROJ + D_INNER + c] * cw[c * 4 + k];
    }
  }
  const float s = acc / (1.f + __expf(-acc));   // silu
  xbc[idx] = s;
  if (c >= D_INNER) BCbf[(size_t)bt * 256 + (c - D_INNER)] = f2bf(s);
}

// ---------------------------------------------------------------------------
// K0: dt = softplus(raw+bias); csum = chunk-local inclusive prefix of dt*A.
// grid 64 = (b,h); block 512 (wave == one 64-chunk).
// ---------------------------------------------------------------------------
__global__ __launch_bounds__(512) void dtcsum(const float* __restrict__ zx,
                                              const float* __restrict__ dt_bias,
                                              const float* __restrict__ A_log,
                                              float* __restrict__ dts,
                                              float* __restrict__ csum) {
  const int bh = blockIdx.x;
  const int b = bh >> 5, h = bh & 31;
  const int t = threadIdx.x;
  const float raw = zx[(size_t)(b * SEQLEN + t) * D_IN_PROJ + (D_INNER + CONV_DIM) + h]
                  + dt_bias[h];
  const float sp = (raw > 20.f) ? raw : log1pf(__expf(raw));
  const float An = -__expf(A_log[h]);
  float x = sp * An;
  #pragma unroll
  for (int off = 1; off < 64; off <<= 1) {
    const float v = __shfl_up(x, off);
    if ((t & 63) >= off) x += v;
  }
  dts[(size_t)bh * SEQLEN + t]  = sp;
  csum[(size_t)bh * SEQLEN + t] = x;
}

// ---------------------------------------------------------------------------
// K1 (fused G + intra): per (b,h,c):
//   G[t][s] = C_t·B_s (8 MFMA, direct-global frags, recomputed per h — cheap)
//   Ml = G∘L in-reg -> bf16 LDS; Yi = Ml·X; dS = Bw·X.
// grid 512; 256 thr. LDS rows padded to 72 shorts (2-way alias, free).
// ---------------------------------------------------------------------------
__global__ __launch_bounds__(256) void chunk_intra(const float* __restrict__ xbc,
                                                   const ushort* __restrict__ BCbf,
                                                   const float* __restrict__ dts,
                                                   const float* __restrict__ csum,
                                                   ushort* __restrict__ Yi,
                                                   ushort* __restrict__ dS) {
  const int blk = blockIdx.x;
  const int c = blk & 7, h = (blk >> 3) & 31, b = blk >> 8;
  const int bh = b * 32 + h;
  const int tid = threadIdx.x, lane = tid & 63, wave = tid >> 6;
  const int r16 = lane & 15, q = lane >> 4;

  __shared__ ushort Ml[64 * 72];
  __shared__ ushort Xt[64 * 72];
  __shared__ ushort Bw[128 * 72];
  __shared__ float dtl[LC], csl[LC];

  if (tid < LC) {
    dtl[tid] = dts[(size_t)bh * SEQLEN + c * LC + tid];
    csl[tid] = csum[(size_t)bh * SEQLEN + c * LC + tid];
  }
  __syncthreads();
  const float cs63 = csl[LC - 1];

  // --- G = C·B^T in-reg (K=128 over n) ---
  const ushort* Cp = BCbf + (size_t)(b * SEQLEN + c * LC + wave * 16 + r16) * 256 + 128 + q * 8;
  const ushort* Bp = BCbf + (size_t)(b * SEQLEN + c * LC + r16) * 256 + q * 8;
  f32x4 g[4] = {};
  #pragma unroll
  for (int kk = 0; kk < 4; ++kk) {
    const bf16x8 a = *(const bf16x8*)(const void*)(Cp + kk * 32);
    #pragma unroll
    for (int j = 0; j < 4; ++j) {
      const bf16x8 bb = *(const bf16x8*)(const void*)(Bp + (size_t)j * 16 * 256 + kk * 32);
      g[j] = __builtin_amdgcn_mfma_f32_16x16x32_bf16(a, bb, g[j], 0, 0, 0);
    }
  }
  // --- Ml = G∘L straight from regs (acc layout: row=wave*16+q*4+r, col=j*16+r16)
  float cst[4];
  #pragma unroll
  for (int r = 0; r < 4; ++r) cst[r] = csl[wave * 16 + q * 4 + r];
  #pragma unroll
  for (int j = 0; j < 4; ++j) {
    const int s = j * 16 + r16;
    const float ds_ = dtl[s], css = csl[s];
    #pragma unroll
    for (int r = 0; r < 4; ++r) {
      const int t = wave * 16 + q * 4 + r;
      const float v = (s <= t) ? g[j][r] * ds_ * __expf(cst[r] - css) : 0.f;
      Ml[t * 72 + s] = f2bf(v);
    }
  }

  // --- stage X^T and Bw ---
  const float* xb = xbc + (size_t)(b * SEQLEN + c * LC) * CONV_DIM + h * HEADDIM;
  #pragma unroll
  for (int i = 0; i < 16; ++i) {
    const int idx = i * 256 + tid;
    const int s = idx >> 6, p = idx & 63;
    Xt[p * 72 + s] = f2bf(xb[(size_t)s * CONV_DIM + p]);
  }
  const float* Bb = xbc + (size_t)(b * SEQLEN + c * LC) * CONV_DIM + D_INNER;
  #pragma unroll
  for (int i = 0; i < 32; ++i) {
    const int idx = i * 256 + tid;
    const int s = idx >> 7, n = idx & 127;
    const float w = dtl[s] * __expf(cs63 - csl[s]);
    Bw[n * 72 + s] = f2bf(Bb[(size_t)s * CONV_DIM + n] * w);
  }
  __syncthreads();

  f32x4 accY[4] = {};
  f32x4 accS[2][4] = {};
  #pragma unroll
  for (int kk = 0; kk < 2; ++kk) {
    const bf16x8 am = *(const bf16x8*)(const void*)(Ml + (wave * 16 + r16) * 72 + kk * 32 + q * 8);
    const bf16x8 a0 = *(const bf16x8*)(const void*)(Bw + (wave * 32 + r16) * 72 + kk * 32 + q * 8);
    const bf16x8 a1 = *(const bf16x8*)(const void*)(Bw + (wave * 32 + 16 + r16) * 72 + kk * 32 + q * 8);
    #pragma unroll
    for (int j = 0; j < 4; ++j) {
      const bf16x8 bx = *(const bf16x8*)(const void*)(Xt + (j * 16 + r16) * 72 + kk * 32 + q * 8);
      accY[j]    = __builtin_amdgcn_mfma_f32_16x16x32_bf16(am, bx, accY[j], 0, 0, 0);
      accS[0][j] = __builtin_amdgcn_mfma_f32_16x16x32_bf16(a0, bx, accS[0][j], 0, 0, 0);
      accS[1][j] = __builtin_amdgcn_mfma_f32_16x16x32_bf16(a1, bx, accS[1][j], 0, 0, 0);
    }
  }

  ushort* Yp = Yi + (size_t)blk * 4096;
  #pragma unroll
  for (int j = 0; j < 4; ++j)
    #pragma unroll
    for (int r = 0; r < 4; ++r)
      Yp[(wave * 16 + q * 4 + r) * 64 + j * 16 + r16] = f2bf(accY[j][r]);

  ushort* Sp = dS + (size_t)blk * 8192;
  #pragma unroll
  for (int u = 0; u < 2; ++u)
    #pragma unroll
    for (int j = 0; j < 4; ++j)
      #pragma unroll
      for (int r = 0; r < 4; ++r)
        Sp[(wave * 32 + u * 16 + q * 4 + r) * 64 + j * 16 + r16] = f2bf(accS[u][j][r]);
}

// ---------------------------------------------------------------------------
// K2: sequential chunk-state carry. grid 64 = (b,h); 256 thr.
// ---------------------------------------------------------------------------
__global__ __launch_bounds__(256) void chunk_state(const ushort* __restrict__ dS,
                                                   const float* __restrict__ csum,
                                                   ushort* __restrict__ St) {
  const int bh = blockIdx.x;
  const int tid = threadIdx.x;
  const int p = tid & 63, n0 = (tid >> 6) * 32;
  float S[32] = {};
  for (int c = 0; c < NCH; ++c) {
    const size_t base = ((size_t)bh * 8 + c) * 8192;
    uint4 pk[4];
    unsigned* pw = (unsigned*)pk;
    #pragma unroll
    for (int j = 0; j < 16; ++j)
      pw[j] = (unsigned)f2bf(S[2 * j]) | ((unsigned)f2bf(S[2 * j + 1]) << 16);
    uint4* dst = (uint4*)(St + base + (size_t)p * 128 + n0);
    #pragma unroll
    for (int j = 0; j < 4; ++j) dst[j] = pk[j];
    const float e = __expf(csum[(size_t)bh * SEQLEN + c * LC + (LC - 1)]);
    #pragma unroll
    for (int j = 0; j < 32; ++j) {
      const float d = bf2f(dS[base + (size_t)(n0 + j) * 64 + p]);
      S[j] = S[j] * e + d;
    }
  }
}

// ---------------------------------------------------------------------------
// K3: Y[t][p] = exp(cs[t]) * (C_t · S_start) + Yi[t][p] + D_h * x[t][p]
// ---------------------------------------------------------------------------
__global__ __launch_bounds__(256) void chunk_inter(const ushort* __restrict__ BCbf,
                                                   const ushort* __restrict__ St,
                                                   const ushort* __restrict__ Yi,
                                                   const float* __restrict__ xbc,
                                                   const float* __restrict__ csum,
                                                   const float* __restrict__ Dp,
                                                   float* __restrict__ y) {
  const int blk = blockIdx.x;
  const int c = blk & 7, h = (blk >> 3) & 31, b = blk >> 8;
  const int bh = b * 32 + h;
  const int tid = threadIdx.x, lane = tid & 63, wave = tid >> 6;
  const int r16 = lane & 15, q = lane >> 4;

  const ushort* Cp = BCbf + (size_t)(b * SEQLEN + c * LC + wave * 16 + r16) * 256 + 128 + q * 8;
  const ushort* Sp = St + (size_t)blk * 8192 + (size_t)r16 * 128 + q * 8;
  f32x4 acc[4] = {};
  #pragma unroll
  for (int kk = 0; kk < 4; ++kk) {
    const bf16x8 a = *(const bf16x8*)(const void*)(Cp + kk * 32);
    #pragma unroll
    for (int j = 0; j < 4; ++j) {
      const bf16x8 bb = *(const bf16x8*)(const void*)(Sp + (size_t)j * 16 * 128 + kk * 32);
      acc[j] = __builtin_amdgcn_mfma_f32_16x16x32_bf16(a, bb, acc[j], 0, 0, 0);
    }
  }

  const float Dh = Dp[h];
  const ushort* Yp = Yi + (size_t)blk * 4096;
  float sc[4];
  #pragma unroll
  for (int r = 0; r < 4; ++r)
    sc[r] = __expf(csum[(size_t)bh * SEQLEN + c * LC + wave * 16 + q * 4 + r]);
  #pragma unroll
  for (int j = 0; j < 4; ++j) {
    const int col = j * 16 + r16;
    #pragma unroll
    for (int r = 0; r < 4; ++r) {
      const int t = wave * 16 + q * 4 + r;
      const size_t row = (size_t)(b * SEQLEN + c * LC + t);
      const float xv = xbc[row * CONV_DIM + h * HEADDIM + col];
      y[row * D_INNER + h * HEADDIM + col] =
          acc[j][r] * sc[r] + bf2f(Yp[t * 64 + col]) + Dh * xv;
    }
  }
}

// ---------------------------------------------------------------------------
// y + gate silu(z), RMSNorm -> bf16 yn
// ---------------------------------------------------------------------------
__global__ __launch_bounds__(256) void gate_norm(const float* __restrict__ y,
                                                 const float* __restrict__ zx,
                                                 const float* __restrict__ nw,
                                                 ushort* __restrict__ yn) {
  const int row = blockIdx.x;
  const int tid = threadIdx.x;
  float vals[8];
  float ss = 0.f;
  #pragma unroll
  for (int i = 0; i < 8; ++i) {
    const int e = tid + i * 256;
    const float yv = y[(size_t)row * D_INNER + e];
    const float z = zx[(size_t)row * D_IN_PROJ + e];
    const float g = z / (1.f + __expf(-z));   // silu(z)
    const float yg = yv * g;
    vals[i] = yg;
    ss = fmaf(yg, yg, ss);
  }
  for (int o = 32; o > 0; o >>= 1) ss += __shfl_down(ss, o);
  __shared__ float wsum[4];
  if ((tid & 63) == 0) wsum[tid >> 6] = ss;
  __syncthreads();
  const float tot = wsum[0] + wsum[1] + wsum[2] + wsum[3];
  const float rms = rsqrtf(tot * (1.f / D_INNER) + EPS);
  #pragma unroll
  for (int i = 0; i < 8; ++i) {
    const int e = tid + i * 256;
    yn[(size_t)row * D_INNER + e] = f2bf(vals[i] * rms * nw[e]);
  }
}

// ---------------------------------------------------------------------------
extern "C" void kernel_launch(void* const* d_in, const int* in_sizes, int n_in,
                              void* d_out, int out_size, void* d_ws, size_t ws_size,
                              hipStream_t stream) {
  const float* u       = (const float*)d_in[0];
  const float* W_in    = (const float*)d_in[1];
  const float* conv_w  = (const float*)d_in[2];
  const float* conv_b  = (const float*)d_in[3];
  const float* dt_bias = (const float*)d_in[4];
  const float* A_log   = (const float*)d_in[5];
  const float* D_par   = (const float*)d_in[6];
  const float* norm_w  = (const float*)d_in[7];
  const float* W_out   = (const float*)d_in[8];
  float* out = (float*)d_out;

  char* ws = (char*)d_ws;
  // ws layout (bytes), 16B-aligned:
  //   zx      fp32 [1024][4384]      17,956,864  @ 0
  //   xbc     fp32 [1024][2304]       9,437,184  @ 17,956,864
  //   y       fp32 [1024][2048]       8,388,608  @ 27,394,048
  //   yn      bf16 [1024][2048]       4,194,304  @ 35,782,656
  //   u_bf    bf16 [1024][1024]       2,097,152  @ 39,976,960   (dead after in_proj)
  //   Win_bf  bf16 [4384][1024]       8,978,432  @ 42,074,112   (dead after in_proj)
  //   Yi      bf16 [512][64][64]      4,194,304  @ 39,976,960   ALIAS of u_bf+Win_bf
  //   Wout_bf bf16 [1024][2048]       4,194,304  @ 51,052,544
  //   BC_bf   bf16 [1024][256]          524,288  @ 55,246,848
  //   dts     fp32 [64][512]            131,072  @ 55,771,136
  //   csum    fp32 [64][512]            131,072  @ 55,902,208
  //   dS      bf16 [512][128][64]     8,388,608  @ 56,295,424
  //   St      bf16 [512][64][128]     8,388,608  @ 64,684,032   (end 73,072,640)
  // in_proj reads Bt rows to 4480 -> spills past Win_bf into Wout_bf region
  // (finite bf16, masked on store). Keep Wout_bf adjacent after Win_bf.
  float*  zx      = (float*)ws;
  float*  xbc     = (float*)(ws + 17956864);
  float*  yb      = (float*)(ws + 27394048);
  ushort* yn      = (ushort*)(ws + 35782656);
  ushort* u_bf    = (ushort*)(ws + 39976960);
  ushort* Win_bf  = (ushort*)(ws + 42074112);
  ushort* Yi      = (ushort*)(ws + 39976960);
  ushort* Wout_bf = (ushort*)(ws + 51052544);
  ushort* BC_bf   = (ushort*)(ws + 55246848);
  float*  dts     = (float*)(ws + 55771136);
  float*  csum    = (float*)(ws + 55902208);
  ushort* dS      = (ushort*)(ws + 56295424);
  ushort* St      = (ushort*)(ws + 64684032);

  hipMemsetAsync(out, 0, (size_t)M_TOKENS * D_MODEL * sizeof(float), stream);

  const int n_u = M_TOKENS * D_MODEL, n_wi = D_IN_PROJ * D_MODEL, n_wo = D_MODEL * D_INNER;
  cvt3<<<(n_u + n_wi + n_wo) / (256 * 8), 256, 0, stream>>>(
      u, u_bf, n_u, W_in, Win_bf, n_wi, W_out, Wout_bf, n_wo);

  // in_proj: M=1024, N=4384 (grid padded to 4480), K=1024 — 560 blocks
  gemm_tile<128, 64, 1><<<dim3(NPROJ_PAD / 64, M_TOKENS / 128), 256, 0, stream>>>(
      u_bf, Win_bf, zx, D_IN_PROJ, D_MODEL, D_IN_PROJ);
  conv_silu<<<(M_TOKENS * CONV_DIM) / 256, 256, 0, stream>>>(zx, conv_w, conv_b, xbc, BC_bf);

  dtcsum<<<BATCH * NHEADS, 512, 0, stream>>>(zx, dt_bias, A_log, dts, csum);
  chunk_intra<<<BATCH * NHEADS * NCH, 256, 0, stream>>>(xbc, BC_bf, dts, csum, Yi, dS);
  chunk_state<<<BATCH * NHEADS, 256, 0, stream>>>(dS, csum, St);
  chunk_inter<<<BATCH * NHEADS * NCH, 256, 0, stream>>>(BC_bf, St, Yi, xbc, csum, D_par, yb);

  gate_norm<<<M_TOKENS, 256, 0, stream>>>(yb, zx, norm_w, yn);
  // out_proj: M=1024, N=1024, K=2048 split into 2x1024 — 512 blocks, atomic acc
  gemm_sk<<<dim3(D_MODEL / 64, M_TOKENS / 64, 2), 256, 0, stream>>>(
      yn, Wout_bf, out, D_INNER / 2, D_INNER, D_MODEL);
}

// Round 7
// 188.898 us; speedup vs baseline: 2.5808x; 1.0289x over previous
//
#include <hip/hip_runtime.h>
#include <hip/hip_bf16.h>

#define D_MODEL   1024
#define D_STATE   128
#define D_INNER   2048
#define NHEADS    32
#define HEADDIM   64
#define D_IN_PROJ 4384   // 2*D_INNER + 2*D_STATE + NHEADS
#define NPROJ_PAD 4480   // GEMM tile padding; stores masked to 4384
#define CONV_DIM  2304   // D_INNER + 2*D_STATE
#define BATCH     2
#define SEQLEN    512
#define M_TOKENS  (BATCH*SEQLEN)   // 1024
#define EPS       1e-5f
#define LC        64               // SSD chunk length
#define NCH       (SEQLEN/LC)      // 8 chunks

typedef __bf16 bf16x8 __attribute__((ext_vector_type(8)));
typedef float  f32x4  __attribute__((ext_vector_type(4)));

__device__ __forceinline__ ushort f2bf(float f) {
  union { float f; unsigned int i; } v; v.f = f;
  unsigned int x = v.i;
  return (ushort)((x + 0x7fffu + ((x >> 16) & 1u)) >> 16);
}
__device__ __forceinline__ float bf2f(ushort u) {
  union { unsigned int i; float f; } v; v.i = ((unsigned int)u) << 16; return v.f;
}

__device__ __forceinline__ void gload_lds16u(const ushort* g, ushort* l) {
  __builtin_amdgcn_global_load_lds(
      (const __attribute__((address_space(1))) void*)g,
      (__attribute__((address_space(3))) void*)l, 16, 0, 0);
}

// ---------------------------------------------------------------------------
// fused fp32->bf16 conversion: u, W_in, W_out*norm_w (one launch)
// ---------------------------------------------------------------------------
__device__ __forceinline__ void cvt8(const float* __restrict__ s,
                                     ushort* __restrict__ d, int i) {
  const float4 a = *(const float4*)(s + i);
  const float4 b = *(const float4*)(s + i + 4);
  uint4 v;
  v.x = (unsigned)f2bf(a.x) | ((unsigned)f2bf(a.y) << 16);
  v.y = (unsigned)f2bf(a.z) | ((unsigned)f2bf(a.w) << 16);
  v.z = (unsigned)f2bf(b.x) | ((unsigned)f2bf(b.y) << 16);
  v.w = (unsigned)f2bf(b.z) | ((unsigned)f2bf(b.w) << 16);
  *(uint4*)(d + i) = v;
}
__global__ __launch_bounds__(256) void cvt3(const float* __restrict__ s0, ushort* __restrict__ d0, int n0,
                                            const float* __restrict__ s1, ushort* __restrict__ d1, int n1,
                                            const float* __restrict__ s2, ushort* __restrict__ d2, int n2,
                                            const float* __restrict__ nw) {
  const int i = (blockIdx.x * 256 + threadIdx.x) * 8;
  if (i < n0)           cvt8(s0, d0, i);
  else if (i < n0 + n1) cvt8(s1, d1, i - n0);
  else if (i < n0 + n1 + n2) {
    // W_out row-major [n][k], fold norm_w[k] (k = j % D_INNER, 8-aligned)
    const int j = i - n0 - n1;
    const int k = j & (D_INNER - 1);
    const float4 a = *(const float4*)(s2 + j);
    const float4 b = *(const float4*)(s2 + j + 4);
    const float4 wa = *(const float4*)(nw + k);
    const float4 wb = *(const float4*)(nw + k + 4);
    uint4 v;
    v.x = (unsigned)f2bf(a.x * wa.x) | ((unsigned)f2bf(a.y * wa.y) << 16);
    v.y = (unsigned)f2bf(a.z * wa.z) | ((unsigned)f2bf(a.w * wa.w) << 16);
    v.z = (unsigned)f2bf(b.x * wb.x) | ((unsigned)f2bf(b.y * wb.y) << 16);
    v.w = (unsigned)f2bf(b.z * wb.z) | ((unsigned)f2bf(b.w * wb.w) << 16);
    *(uint4*)(d2 + j) = v;
  }
}

// ---------------------------------------------------------------------------
// m97-style tiled GEMM (BM x BN, BK=32), 256 thr / 2x2 waves.
// ---------------------------------------------------------------------------
template <int BM, int BN, int MASK_N>
__global__ __launch_bounds__(256) void gemm_tile(const ushort* __restrict__ A,
                                                 const ushort* __restrict__ Bt,
                                                 float* __restrict__ C,
                                                 int Nreal, int K, int ldc) {
  constexpr int WM = BM / 2, WN = BN / 2, FM = WM / 16, FN = WN / 16;
  constexpr int LA = BM * 4 / 256, LB = BN * 4 / 256;
  __shared__ ushort As[BM * 32];
  __shared__ ushort Bs[BN * 32];
  const int tid = threadIdx.x, lane = tid & 63, wave = tid >> 6;
  const int r16 = lane & 15, q = lane >> 4;
  const int wm = wave & 1, wn = wave >> 1;
  const int m0 = blockIdx.y * BM, n0 = blockIdx.x * BN;

  f32x4 acc[FM][FN] = {};

  for (int k0 = 0; k0 < K; k0 += 32) {
    __syncthreads();
    #pragma unroll
    for (int it = 0; it < LA; ++it) {
      const int idx = it * 256 + tid;
      gload_lds16u(A + (size_t)(m0 + (idx >> 2)) * K + k0 + (idx & 3) * 8,
                   As + (it * 256 + wave * 64) * 8);
    }
    #pragma unroll
    for (int it = 0; it < LB; ++it) {
      const int idx = it * 256 + tid;
      gload_lds16u(Bt + (size_t)(n0 + (idx >> 2)) * K + k0 + (idx & 3) * 8,
                   Bs + (it * 256 + wave * 64) * 8);
    }
    __syncthreads();

    bf16x8 af[FM], bfr[FN];
    #pragma unroll
    for (int i = 0; i < FM; ++i)
      af[i] = *(const bf16x8*)(const void*)(As + (wm * WM + i * 16 + r16) * 32 + q * 8);
    #pragma unroll
    for (int j = 0; j < FN; ++j)
      bfr[j] = *(const bf16x8*)(const void*)(Bs + (wn * WN + j * 16 + r16) * 32 + q * 8);
    #pragma unroll
    for (int i = 0; i < FM; ++i)
      #pragma unroll
      for (int j = 0; j < FN; ++j)
        acc[i][j] = __builtin_amdgcn_mfma_f32_16x16x32_bf16(af[i], bfr[j], acc[i][j], 0, 0, 0);
  }

  #pragma unroll
  for (int i = 0; i < FM; ++i) {
    const int row = m0 + wm * WM + i * 16 + q * 4;
    #pragma unroll
    for (int j = 0; j < FN; ++j) {
      const int col = n0 + wn * WN + j * 16 + r16;
      if (!MASK_N || col < Nreal) {
        #pragma unroll
        for (int r = 0; r < 4; ++r)
          C[(size_t)(row + r) * ldc + col] = acc[i][j][r];
      }
    }
  }
}

// ---------------------------------------------------------------------------
// out_proj split-K GEMM + fused RMS scaling: 64x64 tile, K split in 2
// (blockIdx.z), epilogue: out += acc * rsqrt(sumsq[row]/D_INNER + eps).
// ---------------------------------------------------------------------------
__global__ __launch_bounds__(256) void gemm_sk(const ushort* __restrict__ A,
                                               const ushort* __restrict__ Bt,
                                               float* __restrict__ C,
                                               const float* __restrict__ sumsq,
                                               int Khalf, int ldab, int ldc) {
  __shared__ ushort As[64 * 32];
  __shared__ ushort Bs[64 * 32];
  const int tid = threadIdx.x, lane = tid & 63, wave = tid >> 6;
  const int r16 = lane & 15, q = lane >> 4;
  const int wm = wave & 1, wn = wave >> 1;
  const int m0 = blockIdx.y * 64, n0 = blockIdx.x * 64;
  const int kb = blockIdx.z * Khalf;

  f32x4 acc[2][2] = {};
  for (int k0 = 0; k0 < Khalf; k0 += 32) {
    __syncthreads();
    gload_lds16u(A + (size_t)(m0 + (tid >> 2)) * ldab + kb + k0 + (tid & 3) * 8,
                 As + (tid & ~63) * 8);
    gload_lds16u(Bt + (size_t)(n0 + (tid >> 2)) * ldab + kb + k0 + (tid & 3) * 8,
                 Bs + (tid & ~63) * 8);
    __syncthreads();

    bf16x8 af[2], bfr[2];
    #pragma unroll
    for (int i = 0; i < 2; ++i)
      af[i] = *(const bf16x8*)(const void*)(As + (wm * 32 + i * 16 + r16) * 32 + q * 8);
    #pragma unroll
    for (int j = 0; j < 2; ++j)
      bfr[j] = *(const bf16x8*)(const void*)(Bs + (wn * 32 + j * 16 + r16) * 32 + q * 8);
    #pragma unroll
    for (int i = 0; i < 2; ++i)
      #pragma unroll
      for (int j = 0; j < 2; ++j)
        acc[i][j] = __builtin_amdgcn_mfma_f32_16x16x32_bf16(af[i], bfr[j], acc[i][j], 0, 0, 0);
  }

  #pragma unroll
  for (int i = 0; i < 2; ++i) {
    const int row = m0 + wm * 32 + i * 16 + q * 4;
    float rms[4];
    #pragma unroll
    for (int r = 0; r < 4; ++r)
      rms[r] = rsqrtf(sumsq[row + r] * (1.f / D_INNER) + EPS);
    #pragma unroll
    for (int j = 0; j < 2; ++j) {
      const int col = n0 + wn * 32 + j * 16 + r16;
      #pragma unroll
      for (int r = 0; r < 4; ++r)
        unsafeAtomicAdd(&C[(size_t)(row + r) * ldc + col], acc[i][j][r] * rms[r]);
    }
  }
}

// ---------------------------------------------------------------------------
// fused: [blocks 0..1151] causal depthwise conv (k=4) + SiLU, 8-t sliding
// window per thread (11 loads / 8 outputs); [blocks 1152..1215] dt softplus +
// chunk-local prefix csum (one (b,h) per block, wave = one 64-chunk).
// ---------------------------------------------------------------------------
__global__ __launch_bounds__(256) void conv_dt(const float* __restrict__ zx,
                                               const float* __restrict__ cw,
                                               const float* __restrict__ cb,
                                               float* __restrict__ xbc,
                                               ushort* __restrict__ BCbf,
                                               const float* __restrict__ dt_bias,
                                               const float* __restrict__ A_log,
                                               float* __restrict__ dts,
                                               float* __restrict__ csum) {
  const int blk = blockIdx.x;
  if (blk < 1152) {
    const int g  = blk / 9;                       // [0,128) t-group
    const int c  = (blk % 9) * 256 + threadIdx.x; // [0,2304)
    const int b  = g >> 6;
    const int t0 = (g & 63) * 8;
    const float4 w4 = *(const float4*)(cw + c * 4);
    const float bias = cb[c];
    const float* col = zx + (size_t)(b * SEQLEN) * D_IN_PROJ + D_INNER + c;
    float win[11];
    #pragma unroll
    for (int k = 0; k < 11; ++k) {
      const int t = t0 - 3 + k;
      win[k] = (t >= 0) ? col[(size_t)t * D_IN_PROJ] : 0.f;
    }
    #pragma unroll
    for (int i = 0; i < 8; ++i) {
      float a = bias;
      a = fmaf(win[i],     w4.x, a);
      a = fmaf(win[i + 1], w4.y, a);
      a = fmaf(win[i + 2], w4.z, a);
      a = fmaf(win[i + 3], w4.w, a);
      const float s = a / (1.f + __expf(-a));
      const size_t bt = (size_t)(b * SEQLEN + t0 + i);
      xbc[bt * CONV_DIM + c] = s;
      if (c >= D_INNER) BCbf[bt * 256 + (c - D_INNER)] = f2bf(s);
    }
  } else {
    const int bh = blk - 1152;
    const int b = bh >> 5, h = bh & 31;
    const int wave = threadIdx.x >> 6, lane = threadIdx.x & 63;
    const float dtb = dt_bias[h];
    const float An  = -__expf(A_log[h]);
    for (int cc = wave; cc < NCH; cc += 4) {
      const int t = cc * LC + lane;
      const float raw = zx[(size_t)(b * SEQLEN + t) * D_IN_PROJ + (D_INNER + CONV_DIM) + h] + dtb;
      const float sp = (raw > 20.f) ? raw : log1pf(__expf(raw));
      float x = sp * An;
      #pragma unroll
      for (int off = 1; off < 64; off <<= 1) {
        const float v = __shfl_up(x, off);
        if (lane >= off) x += v;
      }
      dts[(size_t)bh * SEQLEN + t]  = sp;
      csum[(size_t)bh * SEQLEN + t] = x;
    }
  }
}

// ---------------------------------------------------------------------------
// K1 (fused G + intra), unchanged from round 5.
// ---------------------------------------------------------------------------
__global__ __launch_bounds__(256) void chunk_intra(const float* __restrict__ xbc,
                                                   const ushort* __restrict__ BCbf,
                                                   const float* __restrict__ dts,
                                                   const float* __restrict__ csum,
                                                   ushort* __restrict__ Yi,
                                                   ushort* __restrict__ dS) {
  const int blk = blockIdx.x;
  const int c = blk & 7, h = (blk >> 3) & 31, b = blk >> 8;
  const int bh = b * 32 + h;
  const int tid = threadIdx.x, lane = tid & 63, wave = tid >> 6;
  const int r16 = lane & 15, q = lane >> 4;

  __shared__ ushort Ml[64 * 72];
  __shared__ ushort Xt[64 * 72];
  __shared__ ushort Bw[128 * 72];
  __shared__ float dtl[LC], csl[LC];

  if (tid < LC) {
    dtl[tid] = dts[(size_t)bh * SEQLEN + c * LC + tid];
    csl[tid] = csum[(size_t)bh * SEQLEN + c * LC + tid];
  }
  __syncthreads();
  const float cs63 = csl[LC - 1];

  const ushort* Cp = BCbf + (size_t)(b * SEQLEN + c * LC + wave * 16 + r16) * 256 + 128 + q * 8;
  const ushort* Bp = BCbf + (size_t)(b * SEQLEN + c * LC + r16) * 256 + q * 8;
  f32x4 g[4] = {};
  #pragma unroll
  for (int kk = 0; kk < 4; ++kk) {
    const bf16x8 a = *(const bf16x8*)(const void*)(Cp + kk * 32);
    #pragma unroll
    for (int j = 0; j < 4; ++j) {
      const bf16x8 bb = *(const bf16x8*)(const void*)(Bp + (size_t)j * 16 * 256 + kk * 32);
      g[j] = __builtin_amdgcn_mfma_f32_16x16x32_bf16(a, bb, g[j], 0, 0, 0);
    }
  }
  float cst[4];
  #pragma unroll
  for (int r = 0; r < 4; ++r) cst[r] = csl[wave * 16 + q * 4 + r];
  #pragma unroll
  for (int j = 0; j < 4; ++j) {
    const int s = j * 16 + r16;
    const float ds_ = dtl[s], css = csl[s];
    #pragma unroll
    for (int r = 0; r < 4; ++r) {
      const int t = wave * 16 + q * 4 + r;
      const float v = (s <= t) ? g[j][r] * ds_ * __expf(cst[r] - css) : 0.f;
      Ml[t * 72 + s] = f2bf(v);
    }
  }

  const float* xb = xbc + (size_t)(b * SEQLEN + c * LC) * CONV_DIM + h * HEADDIM;
  #pragma unroll
  for (int i = 0; i < 16; ++i) {
    const int idx = i * 256 + tid;
    const int s = idx >> 6, p = idx & 63;
    Xt[p * 72 + s] = f2bf(xb[(size_t)s * CONV_DIM + p]);
  }
  const float* Bb = xbc + (size_t)(b * SEQLEN + c * LC) * CONV_DIM + D_INNER;
  #pragma unroll
  for (int i = 0; i < 32; ++i) {
    const int idx = i * 256 + tid;
    const int s = idx >> 7, n = idx & 127;
    const float w = dtl[s] * __expf(cs63 - csl[s]);
    Bw[n * 72 + s] = f2bf(Bb[(size_t)s * CONV_DIM + n] * w);
  }
  __syncthreads();

  f32x4 accY[4] = {};
  f32x4 accS[2][4] = {};
  #pragma unroll
  for (int kk = 0; kk < 2; ++kk) {
    const bf16x8 am = *(const bf16x8*)(const void*)(Ml + (wave * 16 + r16) * 72 + kk * 32 + q * 8);
    const bf16x8 a0 = *(const bf16x8*)(const void*)(Bw + (wave * 32 + r16) * 72 + kk * 32 + q * 8);
    const bf16x8 a1 = *(const bf16x8*)(const void*)(Bw + (wave * 32 + 16 + r16) * 72 + kk * 32 + q * 8);
    #pragma unroll
    for (int j = 0; j < 4; ++j) {
      const bf16x8 bx = *(const bf16x8*)(const void*)(Xt + (j * 16 + r16) * 72 + kk * 32 + q * 8);
      accY[j]    = __builtin_amdgcn_mfma_f32_16x16x32_bf16(am, bx, accY[j], 0, 0, 0);
      accS[0][j] = __builtin_amdgcn_mfma_f32_16x16x32_bf16(a0, bx, accS[0][j], 0, 0, 0);
      accS[1][j] = __builtin_amdgcn_mfma_f32_16x16x32_bf16(a1, bx, accS[1][j], 0, 0, 0);
    }
  }

  ushort* Yp = Yi + (size_t)blk * 4096;
  #pragma unroll
  for (int j = 0; j < 4; ++j)
    #pragma unroll
    for (int r = 0; r < 4; ++r)
      Yp[(wave * 16 + q * 4 + r) * 64 + j * 16 + r16] = f2bf(accY[j][r]);

  ushort* Sp = dS + (size_t)blk * 8192;
  #pragma unroll
  for (int u = 0; u < 2; ++u)
    #pragma unroll
    for (int j = 0; j < 4; ++j)
      #pragma unroll
      for (int r = 0; r < 4; ++r)
        Sp[(wave * 32 + u * 16 + q * 4 + r) * 64 + j * 16 + r16] = f2bf(accS[u][j][r]);
}

// ---------------------------------------------------------------------------
// K2: sequential chunk-state carry (unchanged).
// ---------------------------------------------------------------------------
__global__ __launch_bounds__(256) void chunk_state(const ushort* __restrict__ dS,
                                                   const float* __restrict__ csum,
                                                   ushort* __restrict__ St) {
  const int bh = blockIdx.x;
  const int tid = threadIdx.x;
  const int p = tid & 63, n0 = (tid >> 6) * 32;
  float S[32] = {};
  for (int c = 0; c < NCH; ++c) {
    const size_t base = ((size_t)bh * 8 + c) * 8192;
    uint4 pk[4];
    unsigned* pw = (unsigned*)pk;
    #pragma unroll
    for (int j = 0; j < 16; ++j)
      pw[j] = (unsigned)f2bf(S[2 * j]) | ((unsigned)f2bf(S[2 * j + 1]) << 16);
    uint4* dst = (uint4*)(St + base + (size_t)p * 128 + n0);
    #pragma unroll
    for (int j = 0; j < 4; ++j) dst[j] = pk[j];
    const float e = __expf(csum[(size_t)bh * SEQLEN + c * LC + (LC - 1)]);
    #pragma unroll
    for (int j = 0; j < 32; ++j) {
      const float d = bf2f(dS[base + (size_t)(n0 + j) * 64 + p]);
      S[j] = S[j] * e + d;
    }
  }
}

// ---------------------------------------------------------------------------
// K3 + fused gate: Y = exp(cs_t)*(C_t·S_start) + Yi + D_h*x; yg = Y*silu(z);
// write yn bf16 + atomic per-row sum(yg^2).
// ---------------------------------------------------------------------------
__global__ __launch_bounds__(256) void chunk_inter(const ushort* __restrict__ BCbf,
                                                   const ushort* __restrict__ St,
                                                   const ushort* __restrict__ Yi,
                                                   const float* __restrict__ xbc,
                                                   const float* __restrict__ zx,
                                                   const float* __restrict__ csum,
                                                   const float* __restrict__ Dp,
                                                   ushort* __restrict__ yn,
                                                   float* __restrict__ sumsq) {
  const int blk = blockIdx.x;
  const int c = blk & 7, h = (blk >> 3) & 31, b = blk >> 8;
  const int bh = b * 32 + h;
  const int tid = threadIdx.x, lane = tid & 63, wave = tid >> 6;
  const int r16 = lane & 15, q = lane >> 4;

  const ushort* Cp = BCbf + (size_t)(b * SEQLEN + c * LC + wave * 16 + r16) * 256 + 128 + q * 8;
  const ushort* Sp = St + (size_t)blk * 8192 + (size_t)r16 * 128 + q * 8;
  f32x4 acc[4] = {};
  #pragma unroll
  for (int kk = 0; kk < 4; ++kk) {
    const bf16x8 a = *(const bf16x8*)(const void*)(Cp + kk * 32);
    #pragma unroll
    for (int j = 0; j < 4; ++j) {
      const bf16x8 bb = *(const bf16x8*)(const void*)(Sp + (size_t)j * 16 * 128 + kk * 32);
      acc[j] = __builtin_amdgcn_mfma_f32_16x16x32_bf16(a, bb, acc[j], 0, 0, 0);
    }
  }

  const float Dh = Dp[h];
  const ushort* Yp = Yi + (size_t)blk * 4096;
  float sc[4], ssq[4] = {0.f, 0.f, 0.f, 0.f};
  #pragma unroll
  for (int r = 0; r < 4; ++r)
    sc[r] = __expf(csum[(size_t)bh * SEQLEN + c * LC + wave * 16 + q * 4 + r]);
  #pragma unroll
  for (int j = 0; j < 4; ++j) {
    const int col = j * 16 + r16;
    #pragma unroll
    for (int r = 0; r < 4; ++r) {
      const int t = wave * 16 + q * 4 + r;
      const size_t row = (size_t)(b * SEQLEN + c * LC + t);
      const float xv = xbc[row * CONV_DIM + h * HEADDIM + col];
      const float yv = acc[j][r] * sc[r] + bf2f(Yp[t * 64 + col]) + Dh * xv;
      const float z  = zx[row * D_IN_PROJ + h * HEADDIM + col];
      const float yg = yv * (z / (1.f + __expf(-z)));
      yn[row * D_INNER + h * HEADDIM + col] = f2bf(yg);
      ssq[r] = fmaf(yg, yg, ssq[r]);
    }
  }
  // reduce ssq over the 16 r16-lanes (cols), one atomic per (row) from r16==0
  #pragma unroll
  for (int o = 1; o < 16; o <<= 1) {
    #pragma unroll
    for (int r = 0; r < 4; ++r) ssq[r] += __shfl_xor(ssq[r], o);
  }
  if (r16 == 0) {
    #pragma unroll
    for (int r = 0; r < 4; ++r) {
      const int t = wave * 16 + q * 4 + r;
      unsafeAtomicAdd(&sumsq[b * SEQLEN + c * LC + t], ssq[r]);
    }
  }
}

// ---------------------------------------------------------------------------
extern "C" void kernel_launch(void* const* d_in, const int* in_sizes, int n_in,
                              void* d_out, int out_size, void* d_ws, size_t ws_size,
                              hipStream_t stream) {
  const float* u       = (const float*)d_in[0];
  const float* W_in    = (const float*)d_in[1];
  const float* conv_w  = (const float*)d_in[2];
  const float* conv_b  = (const float*)d_in[3];
  const float* dt_bias = (const float*)d_in[4];
  const float* A_log   = (const float*)d_in[5];
  const float* D_par   = (const float*)d_in[6];
  const float* norm_w  = (const float*)d_in[7];
  const float* W_out   = (const float*)d_in[8];
  float* out = (float*)d_out;

  char* ws = (char*)d_ws;
  // ws layout (bytes), 16B-aligned:
  //   zx      fp32 [1024][4384]      17,956,864  @ 0
  //   xbc     fp32 [1024][2304]       9,437,184  @ 17,956,864
  //   sumsq   fp32 [1024]                 4,096  @ 27,394,048
  //   yn      bf16 [1024][2048]       4,194,304  @ 35,782,656
  //   u_bf    bf16 [1024][1024]       2,097,152  @ 39,976,960   (dead after in_proj)
  //   Win_bf  bf16 [4384][1024]       8,978,432  @ 42,074,112   (dead after in_proj)
  //   Yi      bf16 [512][64][64]      4,194,304  @ 39,976,960   ALIAS of u_bf+Win_bf
  //   Wout_bf bf16 [1024][2048]       4,194,304  @ 51,052,544
  //   BC_bf   bf16 [1024][256]          524,288  @ 55,246,848
  //   dts     fp32 [64][512]            131,072  @ 55,771,136
  //   csum    fp32 [64][512]            131,072  @ 55,902,208
  //   dS      bf16 [512][128][64]     8,388,608  @ 56,295,424
  //   St      bf16 [512][64][128]     8,388,608  @ 64,684,032   (end 73,072,640)
  // in_proj reads Bt rows to 4480 -> spills past Win_bf into Wout_bf region
  // (finite bf16, masked on store). Keep Wout_bf adjacent after Win_bf.
  float*  zx      = (float*)ws;
  float*  xbc     = (float*)(ws + 17956864);
  float*  sumsq   = (float*)(ws + 27394048);
  ushort* yn      = (ushort*)(ws + 35782656);
  ushort* u_bf    = (ushort*)(ws + 39976960);
  ushort* Win_bf  = (ushort*)(ws + 42074112);
  ushort* Yi      = (ushort*)(ws + 39976960);
  ushort* Wout_bf = (ushort*)(ws + 51052544);
  ushort* BC_bf   = (ushort*)(ws + 55246848);
  float*  dts     = (float*)(ws + 55771136);
  float*  csum    = (float*)(ws + 55902208);
  ushort* dS      = (ushort*)(ws + 56295424);
  ushort* St      = (ushort*)(ws + 64684032);

  hipMemsetAsync(out, 0, (size_t)M_TOKENS * D_MODEL * sizeof(float), stream);
  hipMemsetAsync(sumsq, 0, (size_t)M_TOKENS * sizeof(float), stream);

  const int n_u = M_TOKENS * D_MODEL, n_wi = D_IN_PROJ * D_MODEL, n_wo = D_MODEL * D_INNER;
  cvt3<<<(n_u + n_wi + n_wo) / (256 * 8), 256, 0, stream>>>(
      u, u_bf, n_u, W_in, Win_bf, n_wi, W_out, Wout_bf, n_wo, norm_w);

  // in_proj: M=1024, N=4384 (grid padded to 4480), K=1024 — 560 blocks
  gemm_tile<128, 64, 1><<<dim3(NPROJ_PAD / 64, M_TOKENS / 128), 256, 0, stream>>>(
      u_bf, Win_bf, zx, D_IN_PROJ, D_MODEL, D_IN_PROJ);
  // conv+silu (1152 blocks) and dt/csum (64 blocks) fused
  conv_dt<<<1152 + 64, 256, 0, stream>>>(zx, conv_w, conv_b, xbc, BC_bf,
                                         dt_bias, A_log, dts, csum);

  chunk_intra<<<BATCH * NHEADS * NCH, 256, 0, stream>>>(xbc, BC_bf, dts, csum, Yi, dS);
  chunk_state<<<BATCH * NHEADS, 256, 0, stream>>>(dS, csum, St);
  chunk_inter<<<BATCH * NHEADS * NCH, 256, 0, stream>>>(BC_bf, St, Yi, xbc, zx,
                                                        csum, D_par, yn, sumsq);

  // out_proj: M=1024, N=1024, K=2048 split 2x1024 — 512 blocks, rms in epilogue
  gemm_sk<<<dim3(D_MODEL / 64, M_TOKENS / 64, 2), 256, 0, stream>>>(
      yn, Wout_bf, out, sumsq, D_INNER / 2, D_INNER, D_MODEL);
}

// Round 8
// 171.539 us; speedup vs baseline: 2.8419x; 1.1012x over previous
//
#include <hip/hip_runtime.h>
#include <hip/hip_bf16.h>

#define D_MODEL   1024
#define D_STATE   128
#define D_INNER   2048
#define NHEADS    32
#define HEADDIM   64
#define D_IN_PROJ 4384   // 2*D_INNER + 2*D_STATE + NHEADS
#define NPROJ_PAD 4480   // GEMM tile padding; stores masked to 4384
#define CONV_DIM  2304   // D_INNER + 2*D_STATE
#define BATCH     2
#define SEQLEN    512
#define M_TOKENS  (BATCH*SEQLEN)   // 1024
#define EPS       1e-5f
#define LC        64               // SSD chunk length
#define NCH       (SEQLEN/LC)      // 8 chunks

typedef __bf16 bf16x8 __attribute__((ext_vector_type(8)));
typedef float  f32x4  __attribute__((ext_vector_type(4)));

__device__ __forceinline__ ushort f2bf(float f) {
  union { float f; unsigned int i; } v; v.f = f;
  unsigned int x = v.i;
  return (ushort)((x + 0x7fffu + ((x >> 16) & 1u)) >> 16);
}
__device__ __forceinline__ float bf2f(ushort u) {
  union { unsigned int i; float f; } v; v.i = ((unsigned int)u) << 16; return v.f;
}

__device__ __forceinline__ void gload_lds16u(const ushort* g, ushort* l) {
  __builtin_amdgcn_global_load_lds(
      (const __attribute__((address_space(1))) void*)g,
      (__attribute__((address_space(3))) void*)l, 16, 0, 0);
}

// ---------------------------------------------------------------------------
// fused fp32->bf16 conversion: u, W_in, W_out*norm_w (one launch)
// ---------------------------------------------------------------------------
__device__ __forceinline__ void cvt8(const float* __restrict__ s,
                                     ushort* __restrict__ d, int i) {
  const float4 a = *(const float4*)(s + i);
  const float4 b = *(const float4*)(s + i + 4);
  uint4 v;
  v.x = (unsigned)f2bf(a.x) | ((unsigned)f2bf(a.y) << 16);
  v.y = (unsigned)f2bf(a.z) | ((unsigned)f2bf(a.w) << 16);
  v.z = (unsigned)f2bf(b.x) | ((unsigned)f2bf(b.y) << 16);
  v.w = (unsigned)f2bf(b.z) | ((unsigned)f2bf(b.w) << 16);
  *(uint4*)(d + i) = v;
}
__global__ __launch_bounds__(256) void cvt3(const float* __restrict__ s0, ushort* __restrict__ d0, int n0,
                                            const float* __restrict__ s1, ushort* __restrict__ d1, int n1,
                                            const float* __restrict__ s2, ushort* __restrict__ d2, int n2,
                                            const float* __restrict__ nw) {
  const int i = (blockIdx.x * 256 + threadIdx.x) * 8;
  if (i < n0)           cvt8(s0, d0, i);
  else if (i < n0 + n1) cvt8(s1, d1, i - n0);
  else if (i < n0 + n1 + n2) {
    // W_out row-major [n][k], fold norm_w[k] (k = j % D_INNER, 8-aligned)
    const int j = i - n0 - n1;
    const int k = j & (D_INNER - 1);
    const float4 a = *(const float4*)(s2 + j);
    const float4 b = *(const float4*)(s2 + j + 4);
    const float4 wa = *(const float4*)(nw + k);
    const float4 wb = *(const float4*)(nw + k + 4);
    uint4 v;
    v.x = (unsigned)f2bf(a.x * wa.x) | ((unsigned)f2bf(a.y * wa.y) << 16);
    v.y = (unsigned)f2bf(a.z * wa.z) | ((unsigned)f2bf(a.w * wa.w) << 16);
    v.z = (unsigned)f2bf(b.x * wb.x) | ((unsigned)f2bf(b.y * wb.y) << 16);
    v.w = (unsigned)f2bf(b.z * wb.z) | ((unsigned)f2bf(b.w * wb.w) << 16);
    *(uint4*)(d2 + j) = v;
  }
}

// ---------------------------------------------------------------------------
// tiled GEMM, BK=64 as two 32-k LDS panels (halves barrier-drain count;
// per-panel layout keeps global_load_lds contiguous dest + free bank pattern)
// ---------------------------------------------------------------------------
template <int BM, int BN, int MASK_N>
__global__ __launch_bounds__(256) void gemm_tile(const ushort* __restrict__ A,
                                                 const ushort* __restrict__ Bt,
                                                 float* __restrict__ C,
                                                 int Nreal, int K, int ldc) {
  constexpr int WM = BM / 2, WN = BN / 2, FM = WM / 16, FN = WN / 16;
  constexpr int LA = BM * 4 / 256, LB = BN * 4 / 256;   // staging iters / panel
  __shared__ ushort As[2 * BM * 32];
  __shared__ ushort Bs[2 * BN * 32];
  const int tid = threadIdx.x, lane = tid & 63, wave = tid >> 6;
  const int r16 = lane & 15, q = lane >> 4;
  const int wm = wave & 1, wn = wave >> 1;
  const int m0 = blockIdx.y * BM, n0 = blockIdx.x * BN;

  f32x4 acc[FM][FN] = {};

  for (int k0 = 0; k0 < K; k0 += 64) {
    __syncthreads();
    #pragma unroll
    for (int pp = 0; pp < 2; ++pp) {
      #pragma unroll
      for (int it = 0; it < LA; ++it) {
        const int idx = it * 256 + tid;
        gload_lds16u(A + (size_t)(m0 + (idx >> 2)) * K + k0 + pp * 32 + (idx & 3) * 8,
                     As + pp * BM * 32 + (it * 256 + wave * 64) * 8);
      }
      #pragma unroll
      for (int it = 0; it < LB; ++it) {
        const int idx = it * 256 + tid;
        gload_lds16u(Bt + (size_t)(n0 + (idx >> 2)) * K + k0 + pp * 32 + (idx & 3) * 8,
                     Bs + pp * BN * 32 + (it * 256 + wave * 64) * 8);
      }
    }
    __syncthreads();

    #pragma unroll
    for (int pp = 0; pp < 2; ++pp) {
      bf16x8 af[FM], bfr[FN];
      #pragma unroll
      for (int i = 0; i < FM; ++i)
        af[i] = *(const bf16x8*)(const void*)(As + pp * BM * 32 + (wm * WM + i * 16 + r16) * 32 + q * 8);
      #pragma unroll
      for (int j = 0; j < FN; ++j)
        bfr[j] = *(const bf16x8*)(const void*)(Bs + pp * BN * 32 + (wn * WN + j * 16 + r16) * 32 + q * 8);
      #pragma unroll
      for (int i = 0; i < FM; ++i)
        #pragma unroll
        for (int j = 0; j < FN; ++j)
          acc[i][j] = __builtin_amdgcn_mfma_f32_16x16x32_bf16(af[i], bfr[j], acc[i][j], 0, 0, 0);
    }
  }

  #pragma unroll
  for (int i = 0; i < FM; ++i) {
    const int row = m0 + wm * WM + i * 16 + q * 4;
    #pragma unroll
    for (int j = 0; j < FN; ++j) {
      const int col = n0 + wn * WN + j * 16 + r16;
      if (!MASK_N || col < Nreal) {
        #pragma unroll
        for (int r = 0; r < 4; ++r)
          C[(size_t)(row + r) * ldc + col] = acc[i][j][r];
      }
    }
  }
}

// ---------------------------------------------------------------------------
// out_proj split-K GEMM (BK=64, two panels) + fused RMS scaling.
// epilogue: out += acc * rsqrt(sumsq[row]/D_INNER + eps) via unsafeAtomicAdd.
// ---------------------------------------------------------------------------
__global__ __launch_bounds__(256) void gemm_sk(const ushort* __restrict__ A,
                                               const ushort* __restrict__ Bt,
                                               float* __restrict__ C,
                                               const float* __restrict__ sumsq,
                                               int Khalf, int ldab, int ldc) {
  __shared__ ushort As[2 * 64 * 32];
  __shared__ ushort Bs[2 * 64 * 32];
  const int tid = threadIdx.x, lane = tid & 63, wave = tid >> 6;
  const int r16 = lane & 15, q = lane >> 4;
  const int wm = wave & 1, wn = wave >> 1;
  const int m0 = blockIdx.y * 64, n0 = blockIdx.x * 64;
  const int kb = blockIdx.z * Khalf;

  f32x4 acc[2][2] = {};
  for (int k0 = 0; k0 < Khalf; k0 += 64) {
    __syncthreads();
    #pragma unroll
    for (int pp = 0; pp < 2; ++pp) {
      gload_lds16u(A + (size_t)(m0 + (tid >> 2)) * ldab + kb + k0 + pp * 32 + (tid & 3) * 8,
                   As + pp * 64 * 32 + (tid & ~63) * 8);
      gload_lds16u(Bt + (size_t)(n0 + (tid >> 2)) * ldab + kb + k0 + pp * 32 + (tid & 3) * 8,
                   Bs + pp * 64 * 32 + (tid & ~63) * 8);
    }
    __syncthreads();

    #pragma unroll
    for (int pp = 0; pp < 2; ++pp) {
      bf16x8 af[2], bfr[2];
      #pragma unroll
      for (int i = 0; i < 2; ++i)
        af[i] = *(const bf16x8*)(const void*)(As + pp * 64 * 32 + (wm * 32 + i * 16 + r16) * 32 + q * 8);
      #pragma unroll
      for (int j = 0; j < 2; ++j)
        bfr[j] = *(const bf16x8*)(const void*)(Bs + pp * 64 * 32 + (wn * 32 + j * 16 + r16) * 32 + q * 8);
      #pragma unroll
      for (int i = 0; i < 2; ++i)
        #pragma unroll
        for (int j = 0; j < 2; ++j)
          acc[i][j] = __builtin_amdgcn_mfma_f32_16x16x32_bf16(af[i], bfr[j], acc[i][j], 0, 0, 0);
    }
  }

  #pragma unroll
  for (int i = 0; i < 2; ++i) {
    const int row = m0 + wm * 32 + i * 16 + q * 4;
    float rms[4];
    #pragma unroll
    for (int r = 0; r < 4; ++r)
      rms[r] = rsqrtf(sumsq[row + r] * (1.f / D_INNER) + EPS);
    #pragma unroll
    for (int j = 0; j < 2; ++j) {
      const int col = n0 + wn * 32 + j * 16 + r16;
      #pragma unroll
      for (int r = 0; r < 4; ++r)
        unsafeAtomicAdd(&C[(size_t)(row + r) * ldc + col], acc[i][j][r] * rms[r]);
    }
  }
}

// ---------------------------------------------------------------------------
// fused: [blocks 0..1151] causal depthwise conv (k=4) + SiLU, 8-t sliding
// window; [blocks 1152..1215] dt softplus + chunk-local prefix csum.
// ---------------------------------------------------------------------------
__global__ __launch_bounds__(256) void conv_dt(const float* __restrict__ zx,
                                               const float* __restrict__ cw,
                                               const float* __restrict__ cb,
                                               float* __restrict__ xbc,
                                               ushort* __restrict__ BCbf,
                                               const float* __restrict__ dt_bias,
                                               const float* __restrict__ A_log,
                                               float* __restrict__ dts,
                                               float* __restrict__ csum) {
  const int blk = blockIdx.x;
  if (blk < 1152) {
    const int g  = blk / 9;                       // [0,128) t-group
    const int c  = (blk % 9) * 256 + threadIdx.x; // [0,2304)
    const int b  = g >> 6;
    const int t0 = (g & 63) * 8;
    const float4 w4 = *(const float4*)(cw + c * 4);
    const float bias = cb[c];
    const float* col = zx + (size_t)(b * SEQLEN) * D_IN_PROJ + D_INNER + c;
    float win[11];
    #pragma unroll
    for (int k = 0; k < 11; ++k) {
      const int t = t0 - 3 + k;
      win[k] = (t >= 0) ? col[(size_t)t * D_IN_PROJ] : 0.f;
    }
    #pragma unroll
    for (int i = 0; i < 8; ++i) {
      float a = bias;
      a = fmaf(win[i],     w4.x, a);
      a = fmaf(win[i + 1], w4.y, a);
      a = fmaf(win[i + 2], w4.z, a);
      a = fmaf(win[i + 3], w4.w, a);
      const float s = a / (1.f + __expf(-a));
      const size_t bt = (size_t)(b * SEQLEN + t0 + i);
      xbc[bt * CONV_DIM + c] = s;
      if (c >= D_INNER) BCbf[bt * 256 + (c - D_INNER)] = f2bf(s);
    }
  } else {
    const int bh = blk - 1152;
    const int b = bh >> 5, h = bh & 31;
    const int wave = threadIdx.x >> 6, lane = threadIdx.x & 63;
    const float dtb = dt_bias[h];
    const float An  = -__expf(A_log[h]);
    for (int cc = wave; cc < NCH; cc += 4) {
      const int t = cc * LC + lane;
      const float raw = zx[(size_t)(b * SEQLEN + t) * D_IN_PROJ + (D_INNER + CONV_DIM) + h] + dtb;
      const float sp = (raw > 20.f) ? raw : log1pf(__expf(raw));
      float x = sp * An;
      #pragma unroll
      for (int off = 1; off < 64; off <<= 1) {
        const float v = __shfl_up(x, off);
        if (lane >= off) x += v;
      }
      dts[(size_t)bh * SEQLEN + t]  = sp;
      csum[(size_t)bh * SEQLEN + t] = x;
    }
  }
}

// ---------------------------------------------------------------------------
// K1 (fused G + intra), unchanged from round 6.
// ---------------------------------------------------------------------------
__global__ __launch_bounds__(256) void chunk_intra(const float* __restrict__ xbc,
                                                   const ushort* __restrict__ BCbf,
                                                   const float* __restrict__ dts,
                                                   const float* __restrict__ csum,
                                                   ushort* __restrict__ Yi,
                                                   ushort* __restrict__ dS) {
  const int blk = blockIdx.x;
  const int c = blk & 7, h = (blk >> 3) & 31, b = blk >> 8;
  const int bh = b * 32 + h;
  const int tid = threadIdx.x, lane = tid & 63, wave = tid >> 6;
  const int r16 = lane & 15, q = lane >> 4;

  __shared__ ushort Ml[64 * 72];
  __shared__ ushort Xt[64 * 72];
  __shared__ ushort Bw[128 * 72];
  __shared__ float dtl[LC], csl[LC];

  if (tid < LC) {
    dtl[tid] = dts[(size_t)bh * SEQLEN + c * LC + tid];
    csl[tid] = csum[(size_t)bh * SEQLEN + c * LC + tid];
  }
  __syncthreads();
  const float cs63 = csl[LC - 1];

  const ushort* Cp = BCbf + (size_t)(b * SEQLEN + c * LC + wave * 16 + r16) * 256 + 128 + q * 8;
  const ushort* Bp = BCbf + (size_t)(b * SEQLEN + c * LC + r16) * 256 + q * 8;
  f32x4 g[4] = {};
  #pragma unroll
  for (int kk = 0; kk < 4; ++kk) {
    const bf16x8 a = *(const bf16x8*)(const void*)(Cp + kk * 32);
    #pragma unroll
    for (int j = 0; j < 4; ++j) {
      const bf16x8 bb = *(const bf16x8*)(const void*)(Bp + (size_t)j * 16 * 256 + kk * 32);
      g[j] = __builtin_amdgcn_mfma_f32_16x16x32_bf16(a, bb, g[j], 0, 0, 0);
    }
  }
  float cst[4];
  #pragma unroll
  for (int r = 0; r < 4; ++r) cst[r] = csl[wave * 16 + q * 4 + r];
  #pragma unroll
  for (int j = 0; j < 4; ++j) {
    const int s = j * 16 + r16;
    const float ds_ = dtl[s], css = csl[s];
    #pragma unroll
    for (int r = 0; r < 4; ++r) {
      const int t = wave * 16 + q * 4 + r;
      const float v = (s <= t) ? g[j][r] * ds_ * __expf(cst[r] - css) : 0.f;
      Ml[t * 72 + s] = f2bf(v);
    }
  }

  const float* xb = xbc + (size_t)(b * SEQLEN + c * LC) * CONV_DIM + h * HEADDIM;
  #pragma unroll
  for (int i = 0; i < 16; ++i) {
    const int idx = i * 256 + tid;
    const int s = idx >> 6, p = idx & 63;
    Xt[p * 72 + s] = f2bf(xb[(size_t)s * CONV_DIM + p]);
  }
  const float* Bb = xbc + (size_t)(b * SEQLEN + c * LC) * CONV_DIM + D_INNER;
  #pragma unroll
  for (int i = 0; i < 32; ++i) {
    const int idx = i * 256 + tid;
    const int s = idx >> 7, n = idx & 127;
    const float w = dtl[s] * __expf(cs63 - csl[s]);
    Bw[n * 72 + s] = f2bf(Bb[(size_t)s * CONV_DIM + n] * w);
  }
  __syncthreads();

  f32x4 accY[4] = {};
  f32x4 accS[2][4] = {};
  #pragma unroll
  for (int kk = 0; kk < 2; ++kk) {
    const bf16x8 am = *(const bf16x8*)(const void*)(Ml + (wave * 16 + r16) * 72 + kk * 32 + q * 8);
    const bf16x8 a0 = *(const bf16x8*)(const void*)(Bw + (wave * 32 + r16) * 72 + kk * 32 + q * 8);
    const bf16x8 a1 = *(const bf16x8*)(const void*)(Bw + (wave * 32 + 16 + r16) * 72 + kk * 32 + q * 8);
    #pragma unroll
    for (int j = 0; j < 4; ++j) {
      const bf16x8 bx = *(const bf16x8*)(const void*)(Xt + (j * 16 + r16) * 72 + kk * 32 + q * 8);
      accY[j]    = __builtin_amdgcn_mfma_f32_16x16x32_bf16(am, bx, accY[j], 0, 0, 0);
      accS[0][j] = __builtin_amdgcn_mfma_f32_16x16x32_bf16(a0, bx, accS[0][j], 0, 0, 0);
      accS[1][j] = __builtin_amdgcn_mfma_f32_16x16x32_bf16(a1, bx, accS[1][j], 0, 0, 0);
    }
  }

  ushort* Yp = Yi + (size_t)blk * 4096;
  #pragma unroll
  for (int j = 0; j < 4; ++j)
    #pragma unroll
    for (int r = 0; r < 4; ++r)
      Yp[(wave * 16 + q * 4 + r) * 64 + j * 16 + r16] = f2bf(accY[j][r]);

  ushort* Sp = dS + (size_t)blk * 8192;
  #pragma unroll
  for (int u = 0; u < 2; ++u)
    #pragma unroll
    for (int j = 0; j < 4; ++j)
      #pragma unroll
      for (int r = 0; r < 4; ++r)
        Sp[(wave * 32 + u * 16 + q * 4 + r) * 64 + j * 16 + r16] = f2bf(accS[u][j][r]);
}

// ---------------------------------------------------------------------------
// K3 (now also absorbs the chunk-state carry): each block rebuilds its own
// start-state St_c = sum_{c'<c} exp(F_c - F_{c'+1}) dS_{c'} in fp32 regs
// (algebraically identical to the sequential recurrence; exponents <= 0),
// transposes through LDS, then Y = exp(cs_t)*(C_t·St) + Yi + D_h*x,
// gate silu(z), write yn bf16 + atomic per-row sum(yg^2).
// ---------------------------------------------------------------------------
__global__ __launch_bounds__(256) void chunk_inter(const ushort* __restrict__ BCbf,
                                                   const ushort* __restrict__ dS,
                                                   const ushort* __restrict__ Yi,
                                                   const float* __restrict__ xbc,
                                                   const float* __restrict__ zx,
                                                   const float* __restrict__ csum,
                                                   const float* __restrict__ Dp,
                                                   ushort* __restrict__ yn,
                                                   float* __restrict__ sumsq) {
  const int blk = blockIdx.x;
  const int c = blk & 7, h = (blk >> 3) & 31, b = blk >> 8;
  const int bh = b * 32 + h;
  const int tid = threadIdx.x, lane = tid & 63, wave = tid >> 6;
  const int r16 = lane & 15, q = lane >> 4;

  __shared__ ushort Stile[64 * 132];   // [p][n], pad->132 (4-way max, frag reads ~2-way)

  // --- rebuild start state: thread owns p = tid&63, n = n0..n0+31 ---
  const int p  = tid & 63;
  const int n0 = (tid >> 6) * 32;
  float S[32] = {};
  float w = 1.f;
  for (int cp = c - 1; cp >= 0; --cp) {
    const ushort* dp = dS + ((size_t)bh * 8 + cp) * 8192 + (size_t)n0 * 64 + p;
    #pragma unroll
    for (int j = 0; j < 32; ++j)
      S[j] = fmaf(w, bf2f(dp[(size_t)j * 64]), S[j]);
    w *= __expf(csum[(size_t)bh * SEQLEN + cp * LC + (LC - 1)]);
  }
  #pragma unroll
  for (int j = 0; j < 16; ++j) {
    const unsigned v = (unsigned)f2bf(S[2 * j]) | ((unsigned)f2bf(S[2 * j + 1]) << 16);
    *(unsigned*)&Stile[p * 132 + n0 + 2 * j] = v;
  }
  __syncthreads();

  const ushort* Cp = BCbf + (size_t)(b * SEQLEN + c * LC + wave * 16 + r16) * 256 + 128 + q * 8;
  f32x4 acc[4] = {};
  #pragma unroll
  for (int kk = 0; kk < 4; ++kk) {
    const bf16x8 a = *(const bf16x8*)(const void*)(Cp + kk * 32);
    #pragma unroll
    for (int j = 0; j < 4; ++j) {
      const bf16x8 bb = *(const bf16x8*)(const void*)(Stile + (j * 16 + r16) * 132 + kk * 32 + q * 8);
      acc[j] = __builtin_amdgcn_mfma_f32_16x16x32_bf16(a, bb, acc[j], 0, 0, 0);
    }
  }

  const float Dh = Dp[h];
  const ushort* Yp = Yi + (size_t)blk * 4096;
  float sc[4], ssq[4] = {0.f, 0.f, 0.f, 0.f};
  #pragma unroll
  for (int r = 0; r < 4; ++r)
    sc[r] = __expf(csum[(size_t)bh * SEQLEN + c * LC + wave * 16 + q * 4 + r]);
  #pragma unroll
  for (int j = 0; j < 4; ++j) {
    const int col = j * 16 + r16;
    #pragma unroll
    for (int r = 0; r < 4; ++r) {
      const int t = wave * 16 + q * 4 + r;
      const size_t row = (size_t)(b * SEQLEN + c * LC + t);
      const float xv = xbc[row * CONV_DIM + h * HEADDIM + col];
      const float yv = acc[j][r] * sc[r] + bf2f(Yp[t * 64 + col]) + Dh * xv;
      const float z  = zx[row * D_IN_PROJ + h * HEADDIM + col];
      const float yg = yv * (z / (1.f + __expf(-z)));
      yn[row * D_INNER + h * HEADDIM + col] = f2bf(yg);
      ssq[r] = fmaf(yg, yg, ssq[r]);
    }
  }
  #pragma unroll
  for (int o = 1; o < 16; o <<= 1) {
    #pragma unroll
    for (int r = 0; r < 4; ++r) ssq[r] += __shfl_xor(ssq[r], o);
  }
  if (r16 == 0) {
    #pragma unroll
    for (int r = 0; r < 4; ++r) {
      const int t = wave * 16 + q * 4 + r;
      unsafeAtomicAdd(&sumsq[b * SEQLEN + c * LC + t], ssq[r]);
    }
  }
}

// ---------------------------------------------------------------------------
extern "C" void kernel_launch(void* const* d_in, const int* in_sizes, int n_in,
                              void* d_out, int out_size, void* d_ws, size_t ws_size,
                              hipStream_t stream) {
  const float* u       = (const float*)d_in[0];
  const float* W_in    = (const float*)d_in[1];
  const float* conv_w  = (const float*)d_in[2];
  const float* conv_b  = (const float*)d_in[3];
  const float* dt_bias = (const float*)d_in[4];
  const float* A_log   = (const float*)d_in[5];
  const float* D_par   = (const float*)d_in[6];
  const float* norm_w  = (const float*)d_in[7];
  const float* W_out   = (const float*)d_in[8];
  float* out = (float*)d_out;

  char* ws = (char*)d_ws;
  // ws layout (bytes), 16B-aligned:
  //   zx      fp32 [1024][4384]      17,956,864  @ 0
  //   xbc     fp32 [1024][2304]       9,437,184  @ 17,956,864
  //   sumsq   fp32 [1024]                 4,096  @ 27,394,048
  //   yn      bf16 [1024][2048]       4,194,304  @ 35,782,656
  //   u_bf    bf16 [1024][1024]       2,097,152  @ 39,976,960   (dead after in_proj)
  //   Win_bf  bf16 [4384][1024]       8,978,432  @ 42,074,112   (dead after in_proj)
  //   Yi      bf16 [512][64][64]      4,194,304  @ 39,976,960   ALIAS of u_bf+Win_bf
  //   Wout_bf bf16 [1024][2048]       4,194,304  @ 51,052,544
  //   BC_bf   bf16 [1024][256]          524,288  @ 55,246,848
  //   dts     fp32 [64][512]            131,072  @ 55,771,136
  //   csum    fp32 [64][512]            131,072  @ 55,902,208
  //   dS      bf16 [512][128][64]     8,388,608  @ 56,295,424   (end 64,684,032)
  // in_proj reads Bt rows to 4480 -> spills past Win_bf into Wout_bf region
  // (finite bf16, masked on store). Keep Wout_bf adjacent after Win_bf.
  float*  zx      = (float*)ws;
  float*  xbc     = (float*)(ws + 17956864);
  float*  sumsq   = (float*)(ws + 27394048);
  ushort* yn      = (ushort*)(ws + 35782656);
  ushort* u_bf    = (ushort*)(ws + 39976960);
  ushort* Win_bf  = (ushort*)(ws + 42074112);
  ushort* Yi      = (ushort*)(ws + 39976960);
  ushort* Wout_bf = (ushort*)(ws + 51052544);
  ushort* BC_bf   = (ushort*)(ws + 55246848);
  float*  dts     = (float*)(ws + 55771136);
  float*  csum    = (float*)(ws + 55902208);
  ushort* dS      = (ushort*)(ws + 56295424);

  hipMemsetAsync(out, 0, (size_t)M_TOKENS * D_MODEL * sizeof(float), stream);
  hipMemsetAsync(sumsq, 0, (size_t)M_TOKENS * sizeof(float), stream);

  const int n_u = M_TOKENS * D_MODEL, n_wi = D_IN_PROJ * D_MODEL, n_wo = D_MODEL * D_INNER;
  cvt3<<<(n_u + n_wi + n_wo) / (256 * 8), 256, 0, stream>>>(
      u, u_bf, n_u, W_in, Win_bf, n_wi, W_out, Wout_bf, n_wo, norm_w);

  // in_proj: M=1024, N=4384 (grid padded to 4480), K=1024 — 560 blocks, BK=64
  gemm_tile<128, 64, 1><<<dim3(NPROJ_PAD / 64, M_TOKENS / 128), 256, 0, stream>>>(
      u_bf, Win_bf, zx, D_IN_PROJ, D_MODEL, D_IN_PROJ);
  // conv+silu (1152 blocks) and dt/csum (64 blocks) fused
  conv_dt<<<1152 + 64, 256, 0, stream>>>(zx, conv_w, conv_b, xbc, BC_bf,
                                         dt_bias, A_log, dts, csum);

  chunk_intra<<<BATCH * NHEADS * NCH, 256, 0, stream>>>(xbc, BC_bf, dts, csum, Yi, dS);
  chunk_inter<<<BATCH * NHEADS * NCH, 256, 0, stream>>>(BC_bf, dS, Yi, xbc, zx,
                                                        csum, D_par, yn, sumsq);

  // out_proj: M=1024, N=1024, K=2048 split 2x1024 — 512 blocks, rms in epilogue
  gemm_sk<<<dim3(D_MODEL / 64, M_TOKENS / 64, 2), 256, 0, stream>>>(
      yn, Wout_bf, out, sumsq, D_INNER / 2, D_INNER, D_MODEL);
}

// Round 9
// 164.317 us; speedup vs baseline: 2.9668x; 1.0440x over previous
//
#include <hip/hip_runtime.h>
#include <hip/hip_bf16.h>

#define D_MODEL   1024
#define D_STATE   128
#define D_INNER   2048
#define NHEADS    32
#define HEADDIM   64
#define D_IN_PROJ 4384   // 2*D_INNER + 2*D_STATE + NHEADS
#define NPROJ_PAD 4480   // GEMM tile padding; stores masked to 4384
#define CONV_DIM  2304   // D_INNER + 2*D_STATE
#define BATCH     2
#define SEQLEN    512
#define M_TOKENS  (BATCH*SEQLEN)   // 1024
#define EPS       1e-5f
#define LC        64               // SSD chunk length
#define NCH       (SEQLEN/LC)      // 8 chunks

typedef __bf16 bf16x8 __attribute__((ext_vector_type(8)));
typedef float  f32x4  __attribute__((ext_vector_type(4)));

__device__ __forceinline__ ushort f2bf(float f) {
  union { float f; unsigned int i; } v; v.f = f;
  unsigned int x = v.i;
  return (ushort)((x + 0x7fffu + ((x >> 16) & 1u)) >> 16);
}
__device__ __forceinline__ float bf2f(ushort u) {
  union { unsigned int i; float f; } v; v.i = ((unsigned int)u) << 16; return v.f;
}

__device__ __forceinline__ void gload_lds16u(const ushort* g, ushort* l) {
  __builtin_amdgcn_global_load_lds(
      (const __attribute__((address_space(1))) void*)g,
      (__attribute__((address_space(3))) void*)l, 16, 0, 0);
}

// ---------------------------------------------------------------------------
// fused fp32->bf16 conversion (u, W_in, W_out*norm_w) + zero-init of out and
// sumsq (absorbs the two hipMemsetAsync launches). 8 elems/thread.
// ---------------------------------------------------------------------------
__device__ __forceinline__ void cvt8(const float* __restrict__ s,
                                     ushort* __restrict__ d, int i) {
  const float4 a = *(const float4*)(s + i);
  const float4 b = *(const float4*)(s + i + 4);
  uint4 v;
  v.x = (unsigned)f2bf(a.x) | ((unsigned)f2bf(a.y) << 16);
  v.y = (unsigned)f2bf(a.z) | ((unsigned)f2bf(a.w) << 16);
  v.z = (unsigned)f2bf(b.x) | ((unsigned)f2bf(b.y) << 16);
  v.w = (unsigned)f2bf(b.z) | ((unsigned)f2bf(b.w) << 16);
  *(uint4*)(d + i) = v;
}
__global__ __launch_bounds__(256) void cvt3z(const float* __restrict__ s0, ushort* __restrict__ d0, int n0,
                                             const float* __restrict__ s1, ushort* __restrict__ d1, int n1,
                                             const float* __restrict__ s2, ushort* __restrict__ d2, int n2,
                                             const float* __restrict__ nw,
                                             float* __restrict__ zout, int n3,
                                             float* __restrict__ zsum, int n4) {
  const int i = (blockIdx.x * 256 + threadIdx.x) * 8;
  if (i < n0)           cvt8(s0, d0, i);
  else if (i < n0 + n1) cvt8(s1, d1, i - n0);
  else if (i < n0 + n1 + n2) {
    // W_out row-major [n][k], fold norm_w[k] (k = j % D_INNER, 8-aligned)
    const int j = i - n0 - n1;
    const int k = j & (D_INNER - 1);
    const float4 a = *(const float4*)(s2 + j);
    const float4 b = *(const float4*)(s2 + j + 4);
    const float4 wa = *(const float4*)(nw + k);
    const float4 wb = *(const float4*)(nw + k + 4);
    uint4 v;
    v.x = (unsigned)f2bf(a.x * wa.x) | ((unsigned)f2bf(a.y * wa.y) << 16);
    v.y = (unsigned)f2bf(a.z * wa.z) | ((unsigned)f2bf(a.w * wa.w) << 16);
    v.z = (unsigned)f2bf(b.x * wb.x) | ((unsigned)f2bf(b.y * wb.y) << 16);
    v.w = (unsigned)f2bf(b.z * wb.z) | ((unsigned)f2bf(b.w * wb.w) << 16);
    *(uint4*)(d2 + j) = v;
  } else if (i < n0 + n1 + n2 + n3) {
    const int j = i - n0 - n1 - n2;
    const float4 z = {0.f, 0.f, 0.f, 0.f};
    *(float4*)(zout + j) = z;
    *(float4*)(zout + j + 4) = z;
  } else if (i < n0 + n1 + n2 + n3 + n4) {
    const int j = i - n0 - n1 - n2 - n3;
    const float4 z = {0.f, 0.f, 0.f, 0.f};
    *(float4*)(zsum + j) = z;
    *(float4*)(zsum + j + 4) = z;
  }
}

// ---------------------------------------------------------------------------
// tiled GEMM, BK=32*PK LDS panels (global_load_lds contiguous dest preserved
// per panel). bf16 in, bf16 out (masked). 256 thr / 2x2 waves.
// ---------------------------------------------------------------------------
template <int BM, int BN, int PK>
__global__ __launch_bounds__(256) void gemm_tile(const ushort* __restrict__ A,
                                                 const ushort* __restrict__ Bt,
                                                 ushort* __restrict__ C,
                                                 int Nreal, int K, int ldc) {
  constexpr int WM = BM / 2, WN = BN / 2, FM = WM / 16, FN = WN / 16;
  constexpr int LA = BM * 4 / 256, LB = BN * 4 / 256;   // staging iters / panel
  __shared__ ushort As[PK * BM * 32];
  __shared__ ushort Bs[PK * BN * 32];
  const int tid = threadIdx.x, lane = tid & 63, wave = tid >> 6;
  const int r16 = lane & 15, q = lane >> 4;
  const int wm = wave & 1, wn = wave >> 1;
  const int m0 = blockIdx.y * BM, n0 = blockIdx.x * BN;

  f32x4 acc[FM][FN] = {};

  for (int k0 = 0; k0 < K; k0 += 32 * PK) {
    __syncthreads();
    #pragma unroll
    for (int pp = 0; pp < PK; ++pp) {
      #pragma unroll
      for (int it = 0; it < LA; ++it) {
        const int idx = it * 256 + tid;
        gload_lds16u(A + (size_t)(m0 + (idx >> 2)) * K + k0 + pp * 32 + (idx & 3) * 8,
                     As + pp * BM * 32 + (it * 256 + wave * 64) * 8);
      }
      #pragma unroll
      for (int it = 0; it < LB; ++it) {
        const int idx = it * 256 + tid;
        gload_lds16u(Bt + (size_t)(n0 + (idx >> 2)) * K + k0 + pp * 32 + (idx & 3) * 8,
                     Bs + pp * BN * 32 + (it * 256 + wave * 64) * 8);
      }
    }
    __syncthreads();

    #pragma unroll
    for (int pp = 0; pp < PK; ++pp) {
      bf16x8 af[FM], bfr[FN];
      #pragma unroll
      for (int i = 0; i < FM; ++i)
        af[i] = *(const bf16x8*)(const void*)(As + pp * BM * 32 + (wm * WM + i * 16 + r16) * 32 + q * 8);
      #pragma unroll
      for (int j = 0; j < FN; ++j)
        bfr[j] = *(const bf16x8*)(const void*)(Bs + pp * BN * 32 + (wn * WN + j * 16 + r16) * 32 + q * 8);
      #pragma unroll
      for (int i = 0; i < FM; ++i)
        #pragma unroll
        for (int j = 0; j < FN; ++j)
          acc[i][j] = __builtin_amdgcn_mfma_f32_16x16x32_bf16(af[i], bfr[j], acc[i][j], 0, 0, 0);
    }
  }

  #pragma unroll
  for (int i = 0; i < FM; ++i) {
    const int row = m0 + wm * WM + i * 16 + q * 4;
    #pragma unroll
    for (int j = 0; j < FN; ++j) {
      const int col = n0 + wn * WN + j * 16 + r16;
      if (col < Nreal) {
        #pragma unroll
        for (int r = 0; r < 4; ++r)
          C[(size_t)(row + r) * ldc + col] = f2bf(acc[i][j][r]);
      }
    }
  }
}

// ---------------------------------------------------------------------------
// out_proj split-K GEMM (BK=128, 4 panels) + fused RMS scaling.
// epilogue: out += acc * rsqrt(sumsq[row]/D_INNER + eps) via unsafeAtomicAdd.
// ---------------------------------------------------------------------------
__global__ __launch_bounds__(256) void gemm_sk(const ushort* __restrict__ A,
                                               const ushort* __restrict__ Bt,
                                               float* __restrict__ C,
                                               const float* __restrict__ sumsq,
                                               int Khalf, int ldab, int ldc) {
  __shared__ ushort As[4 * 64 * 32];
  __shared__ ushort Bs[4 * 64 * 32];
  const int tid = threadIdx.x, lane = tid & 63, wave = tid >> 6;
  const int r16 = lane & 15, q = lane >> 4;
  const int wm = wave & 1, wn = wave >> 1;
  const int m0 = blockIdx.y * 64, n0 = blockIdx.x * 64;
  const int kb = blockIdx.z * Khalf;

  f32x4 acc[2][2] = {};
  for (int k0 = 0; k0 < Khalf; k0 += 128) {
    __syncthreads();
    #pragma unroll
    for (int pp = 0; pp < 4; ++pp) {
      gload_lds16u(A + (size_t)(m0 + (tid >> 2)) * ldab + kb + k0 + pp * 32 + (tid & 3) * 8,
                   As + pp * 64 * 32 + (tid & ~63) * 8);
      gload_lds16u(Bt + (size_t)(n0 + (tid >> 2)) * ldab + kb + k0 + pp * 32 + (tid & 3) * 8,
                   Bs + pp * 64 * 32 + (tid & ~63) * 8);
    }
    __syncthreads();

    #pragma unroll
    for (int pp = 0; pp < 4; ++pp) {
      bf16x8 af[2], bfr[2];
      #pragma unroll
      for (int i = 0; i < 2; ++i)
        af[i] = *(const bf16x8*)(const void*)(As + pp * 64 * 32 + (wm * 32 + i * 16 + r16) * 32 + q * 8);
      #pragma unroll
      for (int j = 0; j < 2; ++j)
        bfr[j] = *(const bf16x8*)(const void*)(Bs + pp * 64 * 32 + (wn * 32 + j * 16 + r16) * 32 + q * 8);
      #pragma unroll
      for (int i = 0; i < 2; ++i)
        #pragma unroll
        for (int j = 0; j < 2; ++j)
          acc[i][j] = __builtin_amdgcn_mfma_f32_16x16x32_bf16(af[i], bfr[j], acc[i][j], 0, 0, 0);
    }
  }

  #pragma unroll
  for (int i = 0; i < 2; ++i) {
    const int row = m0 + wm * 32 + i * 16 + q * 4;
    float rms[4];
    #pragma unroll
    for (int r = 0; r < 4; ++r)
      rms[r] = rsqrtf(sumsq[row + r] * (1.f / D_INNER) + EPS);
    #pragma unroll
    for (int j = 0; j < 2; ++j) {
      const int col = n0 + wn * 32 + j * 16 + r16;
      #pragma unroll
      for (int r = 0; r < 4; ++r)
        unsafeAtomicAdd(&C[(size_t)(row + r) * ldc + col], acc[i][j][r] * rms[r]);
    }
  }
}

// ---------------------------------------------------------------------------
// fused: [blocks 0..1151] causal depthwise conv (k=4) + SiLU over bf16 zx,
// bf16 out; [blocks 1152..1215] dt softplus + chunk-local prefix csum.
// ---------------------------------------------------------------------------
__global__ __launch_bounds__(256) void conv_dt(const ushort* __restrict__ zx,
                                               const float* __restrict__ cw,
                                               const float* __restrict__ cb,
                                               ushort* __restrict__ xbc,
                                               const float* __restrict__ dt_bias,
                                               const float* __restrict__ A_log,
                                               float* __restrict__ dts,
                                               float* __restrict__ csum) {
  const int blk = blockIdx.x;
  if (blk < 1152) {
    const int g  = blk / 9;                       // [0,128) t-group
    const int c  = (blk % 9) * 256 + threadIdx.x; // [0,2304)
    const int b  = g >> 6;
    const int t0 = (g & 63) * 8;
    const float4 w4 = *(const float4*)(cw + c * 4);
    const float bias = cb[c];
    const ushort* col = zx + (size_t)(b * SEQLEN) * D_IN_PROJ + D_INNER + c;
    float win[11];
    #pragma unroll
    for (int k = 0; k < 11; ++k) {
      const int t = t0 - 3 + k;
      win[k] = (t >= 0) ? bf2f(col[(size_t)t * D_IN_PROJ]) : 0.f;
    }
    #pragma unroll
    for (int i = 0; i < 8; ++i) {
      float a = bias;
      a = fmaf(win[i],     w4.x, a);
      a = fmaf(win[i + 1], w4.y, a);
      a = fmaf(win[i + 2], w4.z, a);
      a = fmaf(win[i + 3], w4.w, a);
      const float s = a / (1.f + __expf(-a));
      xbc[(size_t)(b * SEQLEN + t0 + i) * CONV_DIM + c] = f2bf(s);
    }
  } else {
    const int bh = blk - 1152;
    const int b = bh >> 5, h = bh & 31;
    const int wave = threadIdx.x >> 6, lane = threadIdx.x & 63;
    const float dtb = dt_bias[h];
    const float An  = -__expf(A_log[h]);
    for (int cc = wave; cc < NCH; cc += 4) {
      const int t = cc * LC + lane;
      const float raw = bf2f(zx[(size_t)(b * SEQLEN + t) * D_IN_PROJ + (D_INNER + CONV_DIM) + h]) + dtb;
      const float sp = (raw > 20.f) ? raw : log1pf(__expf(raw));
      float x = sp * An;
      #pragma unroll
      for (int off = 1; off < 64; off <<= 1) {
        const float v = __shfl_up(x, off);
        if (lane >= off) x += v;
      }
      dts[(size_t)bh * SEQLEN + t]  = sp;
      csum[(size_t)bh * SEQLEN + t] = x;
    }
  }
}

// ---------------------------------------------------------------------------
// K1 (fused G + intra). B/C/x all read from bf16 xbc (B at +2048, C at +2176).
// ---------------------------------------------------------------------------
__global__ __launch_bounds__(256) void chunk_intra(const ushort* __restrict__ xbc,
                                                   const float* __restrict__ dts,
                                                   const float* __restrict__ csum,
                                                   ushort* __restrict__ Yi,
                                                   ushort* __restrict__ dS) {
  const int blk = blockIdx.x;
  const int c = blk & 7, h = (blk >> 3) & 31, b = blk >> 8;
  const int bh = b * 32 + h;
  const int tid = threadIdx.x, lane = tid & 63, wave = tid >> 6;
  const int r16 = lane & 15, q = lane >> 4;

  __shared__ ushort Ml[64 * 72];
  __shared__ ushort Xt[64 * 72];
  __shared__ ushort Bw[128 * 72];
  __shared__ float dtl[LC], csl[LC];

  if (tid < LC) {
    dtl[tid] = dts[(size_t)bh * SEQLEN + c * LC + tid];
    csl[tid] = csum[(size_t)bh * SEQLEN + c * LC + tid];
  }
  __syncthreads();
  const float cs63 = csl[LC - 1];

  const ushort* rowbase = xbc + (size_t)(b * SEQLEN + c * LC) * CONV_DIM;
  const ushort* Cp = rowbase + (size_t)(wave * 16 + r16) * CONV_DIM + D_INNER + 128 + q * 8;
  const ushort* Bp = rowbase + (size_t)r16 * CONV_DIM + D_INNER + q * 8;
  f32x4 g[4] = {};
  #pragma unroll
  for (int kk = 0; kk < 4; ++kk) {
    const bf16x8 a = *(const bf16x8*)(const void*)(Cp + kk * 32);
    #pragma unroll
    for (int j = 0; j < 4; ++j) {
      const bf16x8 bb = *(const bf16x8*)(const void*)(Bp + (size_t)j * 16 * CONV_DIM + kk * 32);
      g[j] = __builtin_amdgcn_mfma_f32_16x16x32_bf16(a, bb, g[j], 0, 0, 0);
    }
  }
  float cst[4];
  #pragma unroll
  for (int r = 0; r < 4; ++r) cst[r] = csl[wave * 16 + q * 4 + r];
  #pragma unroll
  for (int j = 0; j < 4; ++j) {
    const int s = j * 16 + r16;
    const float ds_ = dtl[s], css = csl[s];
    #pragma unroll
    for (int r = 0; r < 4; ++r) {
      const int t = wave * 16 + q * 4 + r;
      const float v = (s <= t) ? g[j][r] * ds_ * __expf(cst[r] - css) : 0.f;
      Ml[t * 72 + s] = f2bf(v);
    }
  }

  const ushort* xb = rowbase + h * HEADDIM;
  #pragma unroll
  for (int i = 0; i < 16; ++i) {
    const int idx = i * 256 + tid;
    const int s = idx >> 6, p = idx & 63;
    Xt[p * 72 + s] = xb[(size_t)s * CONV_DIM + p];
  }
  const ushort* Bb = rowbase + D_INNER;
  #pragma unroll
  for (int i = 0; i < 32; ++i) {
    const int idx = i * 256 + tid;
    const int s = idx >> 7, n = idx & 127;
    const float w = dtl[s] * __expf(cs63 - csl[s]);
    Bw[n * 72 + s] = f2bf(bf2f(Bb[(size_t)s * CONV_DIM + n]) * w);
  }
  __syncthreads();

  f32x4 accY[4] = {};
  f32x4 accS[2][4] = {};
  #pragma unroll
  for (int kk = 0; kk < 2; ++kk) {
    const bf16x8 am = *(const bf16x8*)(const void*)(Ml + (wave * 16 + r16) * 72 + kk * 32 + q * 8);
    const bf16x8 a0 = *(const bf16x8*)(const void*)(Bw + (wave * 32 + r16) * 72 + kk * 32 + q * 8);
    const bf16x8 a1 = *(const bf16x8*)(const void*)(Bw + (wave * 32 + 16 + r16) * 72 + kk * 32 + q * 8);
    #pragma unroll
    for (int j = 0; j < 4; ++j) {
      const bf16x8 bx = *(const bf16x8*)(const void*)(Xt + (j * 16 + r16) * 72 + kk * 32 + q * 8);
      accY[j]    = __builtin_amdgcn_mfma_f32_16x16x32_bf16(am, bx, accY[j], 0, 0, 0);
      accS[0][j] = __builtin_amdgcn_mfma_f32_16x16x32_bf16(a0, bx, accS[0][j], 0, 0, 0);
      accS[1][j] = __builtin_amdgcn_mfma_f32_16x16x32_bf16(a1, bx, accS[1][j], 0, 0, 0);
    }
  }

  ushort* Yp = Yi + (size_t)blk * 4096;
  #pragma unroll
  for (int j = 0; j < 4; ++j)
    #pragma unroll
    for (int r = 0; r < 4; ++r)
      Yp[(wave * 16 + q * 4 + r) * 64 + j * 16 + r16] = f2bf(accY[j][r]);

  ushort* Sp = dS + (size_t)blk * 8192;
  #pragma unroll
  for (int u = 0; u < 2; ++u)
    #pragma unroll
    for (int j = 0; j < 4; ++j)
      #pragma unroll
      for (int r = 0; r < 4; ++r)
        Sp[(wave * 32 + u * 16 + q * 4 + r) * 64 + j * 16 + r16] = f2bf(accS[u][j][r]);
}

// ---------------------------------------------------------------------------
// K3: rebuild start-state from dS (closed-form decay), C·St via MFMA,
// add Yi + D*x, gate silu(z), write yn bf16 + atomic per-row sum(yg^2).
// ---------------------------------------------------------------------------
__global__ __launch_bounds__(256) void chunk_inter(const ushort* __restrict__ xbc,
                                                   const ushort* __restrict__ dS,
                                                   const ushort* __restrict__ Yi,
                                                   const ushort* __restrict__ zx,
                                                   const float* __restrict__ csum,
                                                   const float* __restrict__ Dp,
                                                   ushort* __restrict__ yn,
                                                   float* __restrict__ sumsq) {
  const int blk = blockIdx.x;
  const int c = blk & 7, h = (blk >> 3) & 31, b = blk >> 8;
  const int bh = b * 32 + h;
  const int tid = threadIdx.x, lane = tid & 63, wave = tid >> 6;
  const int r16 = lane & 15, q = lane >> 4;

  __shared__ ushort Stile[64 * 132];   // [p][n], pad 132

  const int p  = tid & 63;
  const int n0 = (tid >> 6) * 32;
  float S[32] = {};
  float w = 1.f;
  for (int cp = c - 1; cp >= 0; --cp) {
    const ushort* dp = dS + ((size_t)bh * 8 + cp) * 8192 + (size_t)n0 * 64 + p;
    #pragma unroll
    for (int j = 0; j < 32; ++j)
      S[j] = fmaf(w, bf2f(dp[(size_t)j * 64]), S[j]);
    w *= __expf(csum[(size_t)bh * SEQLEN + cp * LC + (LC - 1)]);
  }
  #pragma unroll
  for (int j = 0; j < 16; ++j) {
    const unsigned v = (unsigned)f2bf(S[2 * j]) | ((unsigned)f2bf(S[2 * j + 1]) << 16);
    *(unsigned*)&Stile[p * 132 + n0 + 2 * j] = v;
  }
  __syncthreads();

  const ushort* rowbase = xbc + (size_t)(b * SEQLEN + c * LC) * CONV_DIM;
  const ushort* Cp = rowbase + (size_t)(wave * 16 + r16) * CONV_DIM + D_INNER + 128 + q * 8;
  f32x4 acc[4] = {};
  #pragma unroll
  for (int kk = 0; kk < 4; ++kk) {
    const bf16x8 a = *(const bf16x8*)(const void*)(Cp + kk * 32);
    #pragma unroll
    for (int j = 0; j < 4; ++j) {
      const bf16x8 bb = *(const bf16x8*)(const void*)(Stile + (j * 16 + r16) * 132 + kk * 32 + q * 8);
      acc[j] = __builtin_amdgcn_mfma_f32_16x16x32_bf16(a, bb, acc[j], 0, 0, 0);
    }
  }

  const float Dh = Dp[h];
  const ushort* Yp = Yi + (size_t)blk * 4096;
  float sc[4], ssq[4] = {0.f, 0.f, 0.f, 0.f};
  #pragma unroll
  for (int r = 0; r < 4; ++r)
    sc[r] = __expf(csum[(size_t)bh * SEQLEN + c * LC + wave * 16 + q * 4 + r]);
  #pragma unroll
  for (int j = 0; j < 4; ++j) {
    const int col = j * 16 + r16;
    #pragma unroll
    for (int r = 0; r < 4; ++r) {
      const int t = wave * 16 + q * 4 + r;
      const size_t row = (size_t)(b * SEQLEN + c * LC + t);
      const float xv = bf2f(xbc[row * CONV_DIM + h * HEADDIM + col]);
      const float yv = acc[j][r] * sc[r] + bf2f(Yp[t * 64 + col]) + Dh * xv;
      const float z  = bf2f(zx[row * D_IN_PROJ + h * HEADDIM + col]);
      const float yg = yv * (z / (1.f + __expf(-z)));
      yn[row * D_INNER + h * HEADDIM + col] = f2bf(yg);
      ssq[r] = fmaf(yg, yg, ssq[r]);
    }
  }
  #pragma unroll
  for (int o = 1; o < 16; o <<= 1) {
    #pragma unroll
    for (int r = 0; r < 4; ++r) ssq[r] += __shfl_xor(ssq[r], o);
  }
  if (r16 == 0) {
    #pragma unroll
    for (int r = 0; r < 4; ++r) {
      const int t = wave * 16 + q * 4 + r;
      unsafeAtomicAdd(&sumsq[b * SEQLEN + c * LC + t], ssq[r]);
    }
  }
}

// ---------------------------------------------------------------------------
extern "C" void kernel_launch(void* const* d_in, const int* in_sizes, int n_in,
                              void* d_out, int out_size, void* d_ws, size_t ws_size,
                              hipStream_t stream) {
  const float* u       = (const float*)d_in[0];
  const float* W_in    = (const float*)d_in[1];
  const float* conv_w  = (const float*)d_in[2];
  const float* conv_b  = (const float*)d_in[3];
  const float* dt_bias = (const float*)d_in[4];
  const float* A_log   = (const float*)d_in[5];
  const float* D_par   = (const float*)d_in[6];
  const float* norm_w  = (const float*)d_in[7];
  const float* W_out   = (const float*)d_in[8];
  float* out = (float*)d_out;

  char* ws = (char*)d_ws;
  // ws layout (bytes), 16B-aligned:
  //   zx_bf   bf16 [1024][4384]       8,978,432  @ 0
  //   xbc_bf  bf16 [1024][2304]       4,718,592  @ 8,978,432
  //   sumsq   fp32 [1024]                 4,096  @ 13,697,024
  //   yn      bf16 [1024][2048]       4,194,304  @ 13,701,120
  //   u_bf    bf16 [1024][1024]       2,097,152  @ 17,895,424   (dead after in_proj)
  //   Win_bf  bf16 [4384][1024]       8,978,432  @ 19,992,576   (dead after in_proj)
  //   Yi      bf16 [512][64][64]      4,194,304  @ 17,895,424   ALIAS u_bf+Win_bf
  //   Wout_bf bf16 [1024][2048]       4,194,304  @ 28,971,008
  //   dts     fp32 [64][512]            131,072  @ 33,165,312
  //   csum    fp32 [64][512]            131,072  @ 33,296,384
  //   dS      bf16 [512][128][64]     8,388,608  @ 33,427,456   (end 41,816,064)
  // in_proj reads Bt rows to 4480 -> 196,608 B past Win_bf into Wout_bf region
  // (finite bf16, written by cvt3z beforehand; results masked on store).
  ushort* zx      = (ushort*)ws;
  ushort* xbc     = (ushort*)(ws + 8978432);
  float*  sumsq   = (float*)(ws + 13697024);
  ushort* yn      = (ushort*)(ws + 13701120);
  ushort* u_bf    = (ushort*)(ws + 17895424);
  ushort* Win_bf  = (ushort*)(ws + 19992576);
  ushort* Yi      = (ushort*)(ws + 17895424);
  ushort* Wout_bf = (ushort*)(ws + 28971008);
  float*  dts     = (float*)(ws + 33165312);
  float*  csum    = (float*)(ws + 33296384);
  ushort* dS      = (ushort*)(ws + 33427456);

  const int n_u = M_TOKENS * D_MODEL, n_wi = D_IN_PROJ * D_MODEL, n_wo = D_MODEL * D_INNER;
  const int n_out = M_TOKENS * D_MODEL, n_ss = M_TOKENS;
  const int n_tot = n_u + n_wi + n_wo + n_out + n_ss;
  cvt3z<<<(n_tot + 2047) / 2048, 256, 0, stream>>>(
      u, u_bf, n_u, W_in, Win_bf, n_wi, W_out, Wout_bf, n_wo, norm_w,
      out, n_out, sumsq, n_ss);

  // in_proj: M=1024, N=4384 (grid padded to 4480), K=1024 — 560 blocks, BK=128
  gemm_tile<128, 64, 4><<<dim3(NPROJ_PAD / 64, M_TOKENS / 128), 256, 0, stream>>>(
      u_bf, Win_bf, zx, D_IN_PROJ, D_MODEL, D_IN_PROJ);
  // conv+silu (1152 blocks) and dt/csum (64 blocks) fused
  conv_dt<<<1152 + 64, 256, 0, stream>>>(zx, conv_w, conv_b, xbc,
                                         dt_bias, A_log, dts, csum);

  chunk_intra<<<BATCH * NHEADS * NCH, 256, 0, stream>>>(xbc, dts, csum, Yi, dS);
  chunk_inter<<<BATCH * NHEADS * NCH, 256, 0, stream>>>(xbc, dS, Yi, zx,
                                                        csum, D_par, yn, sumsq);

  // out_proj: M=1024, N=1024, K=2048 split 2x1024 — 512 blocks, rms in epilogue
  gemm_sk<<<dim3(D_MODEL / 64, M_TOKENS / 64, 2), 256, 0, stream>>>(
      yn, Wout_bf, out, sumsq, D_INNER / 2, D_INNER, D_MODEL);
}